// Round 7
// baseline (654.988 us; speedup 1.0000x reference)
//
#include <hip/hip_runtime.h>
#include <math.h>

#define NB 8
#define NN 1024
#define NC 128
#define INV_TAU (1.0f/0.3f)
#define LOG2E 1.44269504088896340736f
#define EPS_CONV 1e-3f

typedef unsigned short u16;
typedef short bf16x8 __attribute__((ext_vector_type(8)));
typedef float f32x4 __attribute__((ext_vector_type(4)));

__device__ __forceinline__ float wsum(float v){
  #pragma unroll
  for (int o = 32; o > 0; o >>= 1) v += __shfl_xor(v, o, 64);
  return v;
}
__device__ __forceinline__ float wmax(float v){
  #pragma unroll
  for (int o = 32; o > 0; o >>= 1) v = fmaxf(v, __shfl_xor(v, o, 64));
  return v;
}
__device__ __forceinline__ float fexp2(float x){ return __builtin_amdgcn_exp2f(x); }
__device__ __forceinline__ float flog2(float x){ return __builtin_amdgcn_logf(x); }
__device__ __forceinline__ u16 f2bf(float f){     // RNE bf16, any finite sign
  unsigned u = __float_as_uint(f);
  return (u16)((u + 0x7FFFu + ((u >> 16) & 1u)) >> 16);
}
__device__ __forceinline__ float bf2f(u16 h){ return __uint_as_float((unsigned)h << 16); }

__device__ __forceinline__ void load16(const float* __restrict__ base, int lane, float* o){
  float4 a = *(const float4*)(base + 8 * lane);
  float4 b = *(const float4*)(base + 8 * lane + 4);
  float4 c = *(const float4*)(base + 512 + 8 * lane);
  float4 d = *(const float4*)(base + 512 + 8 * lane + 4);
  o[0]=a.x; o[1]=a.y; o[2]=a.z; o[3]=a.w; o[4]=b.x; o[5]=b.y; o[6]=b.z; o[7]=b.w;
  o[8]=c.x; o[9]=c.y; o[10]=c.z; o[11]=c.w; o[12]=d.x; o[13]=d.y; o[14]=d.z; o[15]=d.w;
}

// accs: [0:16) loss | [16:32) lc | [32:48) perm | [48:64) cm | [64:80) gmax | 80 IQ2
__global__ void k_init(float* accs, float* P, float* V, float* conv){
  int i = blockIdx.x * 256 + threadIdx.x;   // 8192 threads
  if (i < 160) accs[i] = 0.0f;
  P[i] = 0.0f; V[i] = 0.0f;
  for (int k = i; k < 30720; k += 8192) conv[k] = 0.0f;
}

// ---- L2 normalize * 20; emit f1 fp32 (for k_fva) + hi/lo bf16 splits of f1,f2
__global__ void k_normalize(const float* __restrict__ feats, float* __restrict__ f1,
                            u16* __restrict__ f1h, u16* __restrict__ f1l,
                            u16* __restrict__ f2h, u16* __restrict__ f2l){
  int vid = blockIdx.x;
  int lane = threadIdx.x;          // 64 threads, 2 floats each
  const float* src = feats + (size_t)vid * NC;
  float2 x = *(const float2*)(src + lane * 2);
  float s = wsum(x.x * x.x + x.y * x.y);
  float sc = 20.0f / fmaxf(sqrtf(s), 1e-12f);
  int batch = vid >> 10, n = vid & 1023;
  size_t off = ((size_t)(batch >> 1) * NN + n) * NC + 2 * lane;
  float2 y; y.x = x.x * sc; y.y = x.y * sc;
  u16 h0 = f2bf(y.x), h1 = f2bf(y.y);
  u16 l0 = f2bf(y.x - bf2f(h0)), l1 = f2bf(y.y - bf2f(h1));
  unsigned hw = (unsigned)h0 | ((unsigned)h1 << 16);
  unsigned lw = (unsigned)l0 | ((unsigned)l1 << 16);
  if (batch & 1){
    *(unsigned*)(f2h + off) = hw; *(unsigned*)(f2l + off) = lw;
  } else {
    *(float2*)(f1 + off) = y;
    *(unsigned*)(f1h + off) = hw; *(unsigned*)(f1l + off) = lw;
  }
}

// ---- MFMA GEMM: C[b][n][m] = sum_k A[b][n][k] * B[(b+rollB)&7][m][k]
// A,B given as bf16 hi/lo splits; 3 cross-term MFMAs (hh, hl, lh). 64x64/block, 32x32/wave.
__global__ __launch_bounds__(256) void k_gemm_mfma(const u16* __restrict__ Ah,
                                                   const u16* __restrict__ Al,
                                                   const u16* __restrict__ Bh,
                                                   const u16* __restrict__ Bl,
                                                   void* __restrict__ Cm,
                                                   int rollB, int q16){
  const float QS12 = 32766.0f / 400.0f;
  int b = blockIdx.z;
  int n0 = blockIdx.y * 64, m0 = blockIdx.x * 64;
  int tid = threadIdx.x, w = tid >> 6, lane = tid & 63;
  int quad = lane >> 4, l15 = lane & 15;
  int wn = (w >> 1) * 32, wm = (w & 1) * 32;
  size_t abase = (size_t)b * NN * NC;
  size_t bbase = (size_t)((b + rollB) & 7) * NN * NC;
  const u16 *pAh[2], *pAl[2], *pBh[2], *pBl[2];
  #pragma unroll
  for (int i = 0; i < 2; i++){
    size_t ao = abase + (size_t)(n0 + wn + i * 16 + l15) * NC + quad * 8;
    pAh[i] = Ah + ao; pAl[i] = Al + ao;
    size_t bo = bbase + (size_t)(m0 + wm + i * 16 + l15) * NC + quad * 8;
    pBh[i] = Bh + bo; pBl[i] = Bl + bo;
  }
  f32x4 z = {0.0f, 0.0f, 0.0f, 0.0f};
  f32x4 acc[2][2] = {{z, z}, {z, z}};
  #pragma unroll
  for (int k0 = 0; k0 < NC; k0 += 32){
    bf16x8 ah[2], al[2], bh[2], bl[2];
    #pragma unroll
    for (int i = 0; i < 2; i++){
      ah[i] = *(const bf16x8*)(pAh[i] + k0);
      al[i] = *(const bf16x8*)(pAl[i] + k0);
      bh[i] = *(const bf16x8*)(pBh[i] + k0);
      bl[i] = *(const bf16x8*)(pBl[i] + k0);
    }
    #pragma unroll
    for (int i = 0; i < 2; i++)
      #pragma unroll
      for (int j = 0; j < 2; j++){
        acc[i][j] = __builtin_amdgcn_mfma_f32_16x16x32_bf16(ah[i], bh[j], acc[i][j], 0, 0, 0);
        acc[i][j] = __builtin_amdgcn_mfma_f32_16x16x32_bf16(ah[i], bl[j], acc[i][j], 0, 0, 0);
        acc[i][j] = __builtin_amdgcn_mfma_f32_16x16x32_bf16(al[i], bh[j], acc[i][j], 0, 0, 0);
      }
  }
  // C/D layout: row(M, our n) = quad*4 + reg, col(N, our m) = lane&15  [m89/m91]
  if (q16){
    short* Cb = (short*)Cm + (size_t)b * NN * NN;
    #pragma unroll
    for (int i = 0; i < 2; i++)
      #pragma unroll
      for (int j = 0; j < 2; j++)
        #pragma unroll
        for (int r = 0; r < 4; r++){
          int n = n0 + wn + i * 16 + quad * 4 + r;
          int m = m0 + wm + j * 16 + l15;
          float q = rintf(fminf(fmaxf(acc[i][j][r] * QS12, -32766.0f), 32766.0f));
          Cb[(size_t)n * NN + m] = (short)(int)q;
        }
  } else {
    float* Cb = (float*)Cm + (size_t)b * NN * NN;
    #pragma unroll
    for (int i = 0; i < 2; i++)
      #pragma unroll
      for (int j = 0; j < 2; j++)
        #pragma unroll
        for (int r = 0; r < 4; r++){
          int n = n0 + wn + i * 16 + quad * 4 + r;
          int m = m0 + wm + j * 16 + l15;
          Cb[(size_t)n * NN + m] = acc[i][j][r];
        }
  }
}

// ---- per-row logsumexp (nat domain, for k_fva)
__global__ void k_rowstats(const float* __restrict__ Mb, float* __restrict__ lse){
  int row = blockIdx.x * 4 + (threadIdx.x >> 6);
  int lane = threadIdx.x & 63;
  const float* p = Mb + (size_t)row * NN;
  float x[16]; float mx = -3.402823466e38f;
  #pragma unroll
  for (int k = 0; k < 16; k++){ x[k] = p[lane + 64 * k]; mx = fmaxf(mx, x[k]); }
  mx = wmax(mx);
  float s = 0.0f;
  #pragma unroll
  for (int k = 0; k < 16; k++) s += expf(x[k] - mx);
  s = wsum(s);
  if (lane == 0) lse[row] = mx + logf(s);
}

// ---- row stats (nat) + argmax + correct_match + global absmax
__global__ void k_rowstats_argmax(const float* __restrict__ Mb, float* __restrict__ lse,
                                  float* __restrict__ accs){
  __shared__ float axs[4];
  int row = blockIdx.x * 4 + (threadIdx.x >> 6);
  int wid = threadIdx.x >> 6;
  int lane = threadIdx.x & 63;
  const float* p = Mb + (size_t)row * NN;
  float x[16]; float mx = -3.402823466e38f; float ax = 0.0f;
  float bm = -3.402823466e38f; int bi = 0;
  #pragma unroll
  for (int k = 0; k < 16; k++){
    x[k] = p[lane + 64 * k];
    mx = fmaxf(mx, x[k]);
    ax = fmaxf(ax, fabsf(x[k]));
    if (x[k] > bm){ bm = x[k]; bi = lane + 64 * k; }
  }
  mx = wmax(mx); ax = wmax(ax);
  #pragma unroll
  for (int o = 32; o > 0; o >>= 1){
    float om = __shfl_xor(bm, o, 64); int oi = __shfl_xor(bi, o, 64);
    if (om > bm || (om == bm && oi < bi)){ bm = om; bi = oi; }
  }
  float s = 0.0f;
  #pragma unroll
  for (int k = 0; k < 16; k++) s += expf(x[k] - mx);
  s = wsum(s);
  if (lane == 0){
    lse[row] = mx + logf(s);
    axs[wid] = ax;
    if (bi == (row & 1023)) atomicAdd(&accs[48 + (blockIdx.x & 15)], 1.0f);
  }
  __syncthreads();
  if (threadIdx.x == 0){
    float a = fmaxf(fmaxf(axs[0], axs[1]), fmaxf(axs[2], axs[3]));
    atomicMax((int*)&accs[64 + (blockIdx.x & 15)], __float_as_int(a));
  }
}

__global__ void k_scale(float* accs){
  if (threadIdx.x == 0){
    float g = 0.0f;
    for (int j = 0; j < 16; j++) g = fmaxf(g, accs[64 + j]);
    accs[80] = (g * INV_TAU * LOG2E) / 32766.0f;   // IQ2
  }
}

// ---- fva_half[z][b,n,c] = sum_{m in half z} exp(M[b,n,m]-lse1[b,n]) * f1[(b+1)&7][m][c]
__global__ __launch_bounds__(256) void k_fva(const float* __restrict__ Mb,
                                             const float* __restrict__ lse1,
                                             const float* __restrict__ f1,
                                             float* __restrict__ fva){
  __shared__ float Ps[64][36];
  __shared__ float Bs[64][128];
  int b = blockIdx.y;
  int z = blockIdx.z;
  int n0 = blockIdx.x * 32;
  int mbase = z * 512;
  const float* Mrow = Mb + (size_t)(b * NN + n0) * NN + mbase;
  const float* fa = f1 + (size_t)((b + 1) & 7) * NN * NC + (size_t)mbase * NC;
  const float* lseb = lse1 + b * NN + n0;
  float* fvaH = fva + (size_t)z * 1048576;
  int tid = threadIdx.x;
  int ty = tid >> 5, tx = tid & 31;
  float acc[4][4] = {};
  for (int mm = 0; mm < 512; mm += 64){
    #pragma unroll
    for (int i = 0; i < 2; i++){
      int t = tid + 256 * i;
      int r = t >> 4, m4 = t & 15;
      float l = lseb[r];
      float4 v = *(const float4*)(Mrow + (size_t)r * NN + mm + m4 * 4);
      Ps[m4*4+0][r] = expf(v.x - l); Ps[m4*4+1][r] = expf(v.y - l);
      Ps[m4*4+2][r] = expf(v.z - l); Ps[m4*4+3][r] = expf(v.w - l);
    }
    #pragma unroll
    for (int i = 0; i < 8; i++){
      int t = tid + 256 * i;
      int m = t >> 5, c4 = t & 31;
      *(float4*)&Bs[m][c4 * 4] = *(const float4*)(fa + (size_t)(mm + m) * NC + c4 * 4);
    }
    __syncthreads();
    #pragma unroll 8
    for (int m = 0; m < 64; m++){
      float4 a4 = *(const float4*)&Ps[m][ty * 4];
      float4 b4 = *(const float4*)&Bs[m][tx * 4];
      acc[0][0] += a4.x*b4.x; acc[0][1] += a4.x*b4.y; acc[0][2] += a4.x*b4.z; acc[0][3] += a4.x*b4.w;
      acc[1][0] += a4.y*b4.x; acc[1][1] += a4.y*b4.y; acc[1][2] += a4.y*b4.z; acc[1][3] += a4.y*b4.w;
      acc[2][0] += a4.z*b4.x; acc[2][1] += a4.z*b4.y; acc[2][2] += a4.z*b4.z; acc[2][3] += a4.z*b4.w;
      acc[3][0] += a4.w*b4.x; acc[3][1] += a4.w*b4.y; acc[3][2] += a4.w*b4.z; acc[3][3] += a4.w*b4.w;
    }
    __syncthreads();
  }
  #pragma unroll
  for (int i = 0; i < 4; i++){
    float4 o = make_float4(acc[i][0], acc[i][1], acc[i][2], acc[i][3]);
    *(float4*)(fvaH + ((size_t)(b * NN + n0 + ty * 4 + i)) * NC + tx * 4) = o;
  }
}

// ---- merge fva halves + bf16 hi/lo split
__global__ __launch_bounds__(256) void k_split(const float* __restrict__ A,
                                               const float* __restrict__ B,
                                               u16* __restrict__ H, u16* __restrict__ L){
  int g = blockIdx.x * 256 + threadIdx.x;   // 262144 threads x 4 elems
  float4 a = ((const float4*)A)[g];
  float4 b = ((const float4*)B)[g];
  float s[4] = { a.x + b.x, a.y + b.y, a.z + b.z, a.w + b.w };
  u16 h[4], l[4];
  #pragma unroll
  for (int k = 0; k < 4; k++){
    h[k] = f2bf(s[k]);
    l[k] = f2bf(s[k] - bf2f(h[k]));
  }
  uint2 hw, lw;
  hw.x = (unsigned)h[0] | ((unsigned)h[1] << 16); hw.y = (unsigned)h[2] | ((unsigned)h[3] << 16);
  lw.x = (unsigned)l[0] | ((unsigned)l[1] << 16); lw.y = (unsigned)l[2] | ((unsigned)l[3] << 16);
  ((uint2*)H)[g] = hw; ((uint2*)L)[g] = lw;
}

// ---- quantize L2 = M*INV_TAU*LOG2E to int16 + transposed copy
__global__ __launch_bounds__(256) void k_quant_t(const float* __restrict__ Mb,
                                                 const float* __restrict__ accs,
                                                 short* __restrict__ Q,
                                                 short* __restrict__ Qt){
  __shared__ float T[64][68];
  float KQ = (INV_TAU * LOG2E) / accs[80];
  int b = blockIdx.z; int n0 = blockIdx.y * 64, m0 = blockIdx.x * 64;
  const float* src = Mb + (size_t)b * NN * NN;
  int tid = threadIdx.x;
  #pragma unroll
  for (int i = 0; i < 4; i++){
    int t = tid + 256 * i; int r = t >> 4, c4 = t & 15;
    float4 v = *(const float4*)(src + (size_t)(n0 + r) * NN + m0 + c4 * 4);
    float q0 = rintf(v.x * KQ);
    float q1 = rintf(v.y * KQ);
    float q2 = rintf(v.z * KQ);
    float q3 = rintf(v.w * KQ);
    T[r][c4*4+0] = q0; T[r][c4*4+1] = q1; T[r][c4*4+2] = q2; T[r][c4*4+3] = q3;
    int2 w;
    w.x = ((int)q0 & 0xFFFF) | ((int)q1 << 16);
    w.y = ((int)q2 & 0xFFFF) | ((int)q3 << 16);
    *(int2*)(Q + ((size_t)(b * NN + n0 + r) * NN + m0 + c4 * 4)) = w;
  }
  __syncthreads();
  #pragma unroll
  for (int i = 0; i < 4; i++){
    int t = tid + 256 * i; int r = t >> 4, c4 = t & 15;
    float q0 = T[c4*4+0][r], q1 = T[c4*4+1][r], q2 = T[c4*4+2][r], q3 = T[c4*4+3][r];
    int2 w;
    w.x = ((int)q0 & 0xFFFF) | ((int)q1 << 16);
    w.y = ((int)q2 & 0xFFFF) | ((int)q3 << 16);
    *(int2*)(Qt + ((size_t)(b * NN + m0 + r) * NN + n0 + c4 * 4)) = w;
  }
}

// ---- sinkhorn half-pass (log2 domain) + convergence early-exit.
// conv[pidx*512 + bank*64]: max |delta| of pass pidx (8 banks); skip if pass pidx-2 < eps.
__global__ __launch_bounds__(256) void k_pass(const short* __restrict__ Q,
                                              const float* __restrict__ invec,
                                              float* __restrict__ outvec,
                                              const float* __restrict__ accs,
                                              float* __restrict__ conv, int pidx){
  __shared__ float sdelta[4];
  if (pidx >= 2){
    const float* cs = conv + (size_t)(pidx - 2) * 512;
    float dm = 0.0f;
    #pragma unroll
    for (int i = 0; i < 8; i++) dm = fmaxf(dm, cs[i * 64]);
    if (dm < EPS_CONV) return;       // converged: potentials frozen
  }
  const float IQ2 = accs[80];
  int tid = threadIdx.x, wid = tid >> 6, lane = tid & 63;
  int row = blockIdx.x * 4 + wid;      // 2048 blocks
  int b = row >> 10;
  float hh[16];
  load16(invec + b * NN, lane, hh);
  const int4* qp = (const int4*)(Q + (size_t)row * NN);
  int4 wa = qp[lane], wb = qp[64 + lane];
  float old = (lane == 0) ? outvec[row] : 0.0f;
  int qq[8] = { wa.x, wa.y, wa.z, wa.w, wb.x, wb.y, wb.z, wb.w };
  float x[16]; float mx = -3.402823466e38f;
  #pragma unroll
  for (int k = 0; k < 8; k++){
    x[2*k]   = fmaf((float)(short)(qq[k]), IQ2, hh[2*k]);
    x[2*k+1] = fmaf((float)(qq[k] >> 16),  IQ2, hh[2*k+1]);
    mx = fmaxf(mx, fmaxf(x[2*k], x[2*k+1]));
  }
  mx = wmax(mx);
  float s = 0.0f;
  #pragma unroll
  for (int k = 0; k < 16; k++) s += fexp2(x[k] - mx);
  s = wsum(s);
  if (lane == 0){
    float nv = -(mx + flog2(s));
    outvec[row] = nv;
    sdelta[wid] = fabsf(nv - old);
  }
  __syncthreads();
  if (tid == 0){
    float m = fmaxf(fmaxf(sdelta[0], sdelta[1]), fmaxf(sdelta[2], sdelta[3]));
    if (m >= EPS_CONV)
      atomicMax((int*)(conv + (size_t)pidx * 512 + (blockIdx.x & 7) * 64),
                __float_as_int(m));
  }
}

// ---- fused final reduction (log2 domain, pc in padded split LDS)
__global__ __launch_bounds__(1024) void k_final(const short* __restrict__ Q,
                                                const short* __restrict__ Q12,
                                                const float* __restrict__ lse2,
                                                const float* __restrict__ P2,
                                                const float* __restrict__ V2,
                                                const float* __restrict__ pc0,
                                                float* __restrict__ accs){
  __shared__ float pcx[1152], pcy[1152], pcz[1152];
  __shared__ float partial[3][16];
  const float IQ2 = accs[80];
  const float IQ12_2 = (400.0f / 32766.0f) * LOG2E;
  int tid = threadIdx.x, wid = tid >> 6, lane = tid & 63;
  int row = blockIdx.x * 16 + wid;     // grid 512
  int b = row >> 10, n = row & 1023;
  {
    int m = tid;
    const float* pg = pc0 + (size_t)b * 3072 + 3 * m;
    float px = pg[0], py = pg[1], pz = pg[2];
    int idx = m + (m >> 3);
    pcx[idx] = px; pcy[idx] = py; pcz[idx] = pz;
  }
  __syncthreads();
  const int4* qp  = (const int4*)(Q   + (size_t)row * NN);
  const int4* qp2 = (const int4*)(Q12 + (size_t)row * NN);
  int4 a1 = qp[lane],  b1 = qp[64 + lane];
  int4 a2 = qp2[lane], b2 = qp2[64 + lane];
  int q1[8] = { a1.x, a1.y, a1.z, a1.w, b1.x, b1.y, b1.z, b1.w };
  int q2[8] = { a2.x, a2.y, a2.z, a2.w, b2.x, b2.y, b2.z, b2.w };
  float L[16], c[16];
  float cmx = -3.402823466e38f;
  #pragma unroll
  for (int k = 0; k < 8; k++){
    L[2*k]   = (float)(short)(q1[k]) * IQ2;
    L[2*k+1] = (float)(q1[k] >> 16)  * IQ2;
    c[2*k]   = (float)(short)(q2[k]) * IQ12_2;
    c[2*k+1] = (float)(q2[k] >> 16)  * IQ12_2;
    cmx = fmaxf(cmx, fmaxf(c[2*k], c[2*k+1]));
  }
  cmx = wmax(cmx);
  float cs = 0.0f;
  #pragma unroll
  for (int k = 0; k < 16; k++) cs += fexp2(c[k] - cmx);
  cs = wsum(cs);
  float lse12r = cmx + flog2(cs);
  float vv[16];
  load16(V2 + b * NN, lane, vv);
  int nidx = n + (n >> 3);
  float qx = pcx[nidx], qy = pcy[nidx], qz = pcz[nidx];
  float c1row = -lse2[row] * LOG2E;
  float Prow = P2[row];
  float sl = 0.0f, slc = 0.0f, spi = 0.0f;
  #pragma unroll
  for (int k = 0; k < 16; k++){
    int m = (k < 8) ? (8 * lane + k) : (512 + 8 * lane + k - 8);
    int midx = m + (m >> 3);
    float e1 = fexp2(fmaf(L[k], 0.3f, c1row));
    float sk = fexp2(L[k] + Prow + vv[k]);
    float e2 = fexp2(c[k] - lse12r);
    float dx = qx - pcx[midx], dy = qy - pcy[midx], dz = qz - pcz[midx];
    float d = sqrtf(sqrtf(dx*dx + dy*dy + dz*dz));
    sl  += d * (e1 + e2);
    slc += fabsf(sk - e1);
    spi += fabsf(((m == n) ? 1.0f : 0.0f) - sk);
  }
  sl = wsum(sl); slc = wsum(slc); spi = wsum(spi);
  if (lane == 0){ partial[0][wid] = sl; partial[1][wid] = slc; partial[2][wid] = spi; }
  __syncthreads();
  if (tid < 3){
    float t = 0.0f;
    #pragma unroll
    for (int i = 0; i < 16; i++) t += partial[tid][i];
    atomicAdd(&accs[tid * 16 + (blockIdx.x & 15)], t);
  }
}

__global__ void k_finalize(const float* __restrict__ accs, float* __restrict__ out){
  if (threadIdx.x == 0){
    float sl = 0, slc = 0, spi = 0, scm = 0;
    for (int j = 0; j < 16; j++){
      sl += accs[j]; slc += accs[16 + j]; spi += accs[32 + j]; scm += accs[48 + j];
    }
    float loss = sl / 1024.0f;
    float Lc   = 3.0f * slc / 1024.0f;
    float perm = 3.0f * spi / 1024.0f;
    float total = loss + Lc;
    out[0] = total / 8.0f;
    out[1] = loss / 8.0f;
    out[2] = Lc / 8.0f;
    out[3] = scm / 8.0f;
    out[4] = perm / 8.0f;
  }
}

extern "C" void kernel_launch(void* const* d_in, const int* in_sizes, int n_in,
                              void* d_out, int out_size, void* d_ws, size_t ws_size,
                              hipStream_t stream){
  const float* feats = (const float*)d_in[0];   // [16,1024,128]
  const float* pc0   = (const float*)d_in[1];   // [8,1024,3]
  float* out = (float*)d_out;                   // 5 scalars

  float* ws   = (float*)d_ws;
  float* f1   = ws;                       // 1,048,576 f
  u16* f1h    = (u16*)(f1 + 1048576);     // 1,048,576 u16
  u16* f1l    = f1h + 1048576;
  u16* f2h    = f1l + 1048576;
  u16* f2l    = f2h + 1048576;
  u16* fvh    = f2l + 1048576;
  u16* fvl    = fvh + 1048576;
  float* fva  = (float*)(fvl + 1048576);  // 2,097,152 f (two halves)
  float* M    = fva + 2097152;            // 8,388,608 f
  short* Q    = (short*)(M + 8388608);    // 8,388,608 s16 (log2-scaled)
  short* Qt   = Q + 8388608;              // 8,388,608 s16 (later reused as Q12)
  float* lse1 = (float*)(Qt + 8388608);   // 8192
  float* lse2 = lse1 + 8192;
  float* P    = lse2 + 8192;
  float* V    = P + 8192;
  float* accs = V + 8192;                 // 160
  float* conv = accs + 160;               // 30720 (60 passes x 512)
  if (ws_size < (size_t)((char*)(conv + 30720) - (char*)ws)) return;

  k_init<<<32, 256, 0, stream>>>(accs, P, V, conv);
  k_normalize<<<16384, 64, 0, stream>>>(feats, f1, f1h, f1l, f2h, f2l);
  // corr_1a = f1 @ roll(f1)^T  (MFMA, hi/lo split)
  k_gemm_mfma<<<dim3(16,16,8), 256, 0, stream>>>(f1h, f1l, f1h, f1l, M, 1, 0);
  k_rowstats<<<2048, 256, 0, stream>>>(M, lse1);
  // f1_via_fa = softmax(corr_1a) @ roll(f1) — m-split x2 (vector)
  k_fva<<<dim3(32,8,2), 256, 0, stream>>>(M, lse1, f1, fva);
  k_split<<<1024, 256, 0, stream>>>(fva, fva + 1048576, fvh, fvl);
  // corr_1a2 = fva @ f2^T  (MFMA)
  k_gemm_mfma<<<dim3(16,16,8), 256, 0, stream>>>(fvh, fvl, f2h, f2l, M, 0, 0);
  k_rowstats_argmax<<<2048, 256, 0, stream>>>(M, lse2, accs);
  k_scale<<<1, 64, 0, stream>>>(accs);
  k_quant_t<<<dim3(16,16,8), 256, 0, stream>>>(M, accs, Q, Qt);
  // sinkhorn: 30 x (row pass -> P, col pass -> V), log2 domain, early-exit
  for (int it = 0; it < 30; it++){
    k_pass<<<2048, 256, 0, stream>>>(Q,  V, P, accs, conv, 2 * it);
    k_pass<<<2048, 256, 0, stream>>>(Qt, P, V, accs, conv, 2 * it + 1);
  }
  // corr_12 = f1 @ f2^T as int16 (MFMA), into the now-dead Qt buffer
  k_gemm_mfma<<<dim3(16,16,8), 256, 0, stream>>>(f1h, f1l, f2h, f2l, Qt, 0, 1);
  k_final<<<512, 1024, 0, stream>>>(Q, Qt, lse2, P, V, pc0, accs);
  k_finalize<<<1, 64, 0, stream>>>(accs, out);
}

// Round 8
// 537.400 us; speedup vs baseline: 1.2188x; 1.2188x over previous
//
#include <hip/hip_runtime.h>
#include <math.h>

#define NB 8
#define NN 1024
#define NC 128
#define INV_TAU (1.0f/0.3f)
#define LOG2E 1.44269504088896340736f

typedef unsigned short u16;
typedef short bf16x8 __attribute__((ext_vector_type(8)));
typedef float f32x4 __attribute__((ext_vector_type(4)));

__device__ __forceinline__ float wsum(float v){
  #pragma unroll
  for (int o = 32; o > 0; o >>= 1) v += __shfl_xor(v, o, 64);
  return v;
}
__device__ __forceinline__ float wmax(float v){
  #pragma unroll
  for (int o = 32; o > 0; o >>= 1) v = fmaxf(v, __shfl_xor(v, o, 64));
  return v;
}
__device__ __forceinline__ float fexp2(float x){ return __builtin_amdgcn_exp2f(x); }
__device__ __forceinline__ float flog2(float x){ return __builtin_amdgcn_logf(x); }
__device__ __forceinline__ u16 f2bf(float f){     // RNE bf16, any finite sign
  unsigned u = __float_as_uint(f);
  return (u16)((u + 0x7FFFu + ((u >> 16) & 1u)) >> 16);
}
__device__ __forceinline__ float bf2f(u16 h){ return __uint_as_float((unsigned)h << 16); }

__device__ __forceinline__ void load16(const float* __restrict__ base, int lane, float* o){
  float4 a = *(const float4*)(base + 8 * lane);
  float4 b = *(const float4*)(base + 8 * lane + 4);
  float4 c = *(const float4*)(base + 512 + 8 * lane);
  float4 d = *(const float4*)(base + 512 + 8 * lane + 4);
  o[0]=a.x; o[1]=a.y; o[2]=a.z; o[3]=a.w; o[4]=b.x; o[5]=b.y; o[6]=b.z; o[7]=b.w;
  o[8]=c.x; o[9]=c.y; o[10]=c.z; o[11]=c.w; o[12]=d.x; o[13]=d.y; o[14]=d.z; o[15]=d.w;
}

// accs: [0:16) loss | [16:32) lc | [32:48) perm | [48:64) cm | [64:80) gmax | 80 IQ2
__global__ void k_init(float* accs, float* P, float* V){
  int i = blockIdx.x * 256 + threadIdx.x;   // 8192 threads
  if (i < 160) accs[i] = 0.0f;
  P[i] = 0.0f; V[i] = 0.0f;
}

// ---- L2 normalize * 20; emit f1 fp32 (for k_fva) + hi/lo bf16 splits of f1,f2
__global__ void k_normalize(const float* __restrict__ feats, float* __restrict__ f1,
                            u16* __restrict__ f1h, u16* __restrict__ f1l,
                            u16* __restrict__ f2h, u16* __restrict__ f2l){
  int vid = blockIdx.x;
  int lane = threadIdx.x;          // 64 threads, 2 floats each
  const float* src = feats + (size_t)vid * NC;
  float2 x = *(const float2*)(src + lane * 2);
  float s = wsum(x.x * x.x + x.y * x.y);
  float sc = 20.0f / fmaxf(sqrtf(s), 1e-12f);
  int batch = vid >> 10, n = vid & 1023;
  size_t off = ((size_t)(batch >> 1) * NN + n) * NC + 2 * lane;
  float2 y; y.x = x.x * sc; y.y = x.y * sc;
  u16 h0 = f2bf(y.x), h1 = f2bf(y.y);
  u16 l0 = f2bf(y.x - bf2f(h0)), l1 = f2bf(y.y - bf2f(h1));
  unsigned hw = (unsigned)h0 | ((unsigned)h1 << 16);
  unsigned lw = (unsigned)l0 | ((unsigned)l1 << 16);
  if (batch & 1){
    *(unsigned*)(f2h + off) = hw; *(unsigned*)(f2l + off) = lw;
  } else {
    *(float2*)(f1 + off) = y;
    *(unsigned*)(f1h + off) = hw; *(unsigned*)(f1l + off) = lw;
  }
}

// ---- MFMA GEMM: C[b][n][m] = sum_k A[b][n][k] * B[(b+rollB)&7][m][k]
// A,B given as bf16 hi/lo splits; 3 cross-term MFMAs (hh, hl, lh). 64x64/block, 32x32/wave.
__global__ __launch_bounds__(256) void k_gemm_mfma(const u16* __restrict__ Ah,
                                                   const u16* __restrict__ Al,
                                                   const u16* __restrict__ Bh,
                                                   const u16* __restrict__ Bl,
                                                   void* __restrict__ Cm,
                                                   int rollB, int q16){
  const float QS12 = 32766.0f / 400.0f;
  int b = blockIdx.z;
  int n0 = blockIdx.y * 64, m0 = blockIdx.x * 64;
  int tid = threadIdx.x, w = tid >> 6, lane = tid & 63;
  int quad = lane >> 4, l15 = lane & 15;
  int wn = (w >> 1) * 32, wm = (w & 1) * 32;
  size_t abase = (size_t)b * NN * NC;
  size_t bbase = (size_t)((b + rollB) & 7) * NN * NC;
  const u16 *pAh[2], *pAl[2], *pBh[2], *pBl[2];
  #pragma unroll
  for (int i = 0; i < 2; i++){
    size_t ao = abase + (size_t)(n0 + wn + i * 16 + l15) * NC + quad * 8;
    pAh[i] = Ah + ao; pAl[i] = Al + ao;
    size_t bo = bbase + (size_t)(m0 + wm + i * 16 + l15) * NC + quad * 8;
    pBh[i] = Bh + bo; pBl[i] = Bl + bo;
  }
  f32x4 z = {0.0f, 0.0f, 0.0f, 0.0f};
  f32x4 acc[2][2] = {{z, z}, {z, z}};
  #pragma unroll
  for (int k0 = 0; k0 < NC; k0 += 32){
    bf16x8 ah[2], al[2], bh[2], bl[2];
    #pragma unroll
    for (int i = 0; i < 2; i++){
      ah[i] = *(const bf16x8*)(pAh[i] + k0);
      al[i] = *(const bf16x8*)(pAl[i] + k0);
      bh[i] = *(const bf16x8*)(pBh[i] + k0);
      bl[i] = *(const bf16x8*)(pBl[i] + k0);
    }
    #pragma unroll
    for (int i = 0; i < 2; i++)
      #pragma unroll
      for (int j = 0; j < 2; j++){
        acc[i][j] = __builtin_amdgcn_mfma_f32_16x16x32_bf16(ah[i], bh[j], acc[i][j], 0, 0, 0);
        acc[i][j] = __builtin_amdgcn_mfma_f32_16x16x32_bf16(ah[i], bl[j], acc[i][j], 0, 0, 0);
        acc[i][j] = __builtin_amdgcn_mfma_f32_16x16x32_bf16(al[i], bh[j], acc[i][j], 0, 0, 0);
      }
  }
  // C/D layout: row(our n) = quad*4 + reg, col(our m) = lane&15  [verified: round 7 absmax 0]
  if (q16){
    short* Cb = (short*)Cm + (size_t)b * NN * NN;
    #pragma unroll
    for (int i = 0; i < 2; i++)
      #pragma unroll
      for (int j = 0; j < 2; j++)
        #pragma unroll
        for (int r = 0; r < 4; r++){
          int n = n0 + wn + i * 16 + quad * 4 + r;
          int m = m0 + wm + j * 16 + l15;
          float q = rintf(fminf(fmaxf(acc[i][j][r] * QS12, -32766.0f), 32766.0f));
          Cb[(size_t)n * NN + m] = (short)(int)q;
        }
  } else {
    float* Cb = (float*)Cm + (size_t)b * NN * NN;
    #pragma unroll
    for (int i = 0; i < 2; i++)
      #pragma unroll
      for (int j = 0; j < 2; j++)
        #pragma unroll
        for (int r = 0; r < 4; r++){
          int n = n0 + wn + i * 16 + quad * 4 + r;
          int m = m0 + wm + j * 16 + l15;
          Cb[(size_t)n * NN + m] = acc[i][j][r];
        }
  }
}

// ---- per-row logsumexp (nat domain, for k_fva)
__global__ void k_rowstats(const float* __restrict__ Mb, float* __restrict__ lse){
  int row = blockIdx.x * 4 + (threadIdx.x >> 6);
  int lane = threadIdx.x & 63;
  const float* p = Mb + (size_t)row * NN;
  float x[16]; float mx = -3.402823466e38f;
  #pragma unroll
  for (int k = 0; k < 16; k++){ x[k] = p[lane + 64 * k]; mx = fmaxf(mx, x[k]); }
  mx = wmax(mx);
  float s = 0.0f;
  #pragma unroll
  for (int k = 0; k < 16; k++) s += expf(x[k] - mx);
  s = wsum(s);
  if (lane == 0) lse[row] = mx + logf(s);
}

// ---- row stats (nat) + argmax + correct_match + global absmax
__global__ void k_rowstats_argmax(const float* __restrict__ Mb, float* __restrict__ lse,
                                  float* __restrict__ accs){
  __shared__ float axs[4];
  int row = blockIdx.x * 4 + (threadIdx.x >> 6);
  int wid = threadIdx.x >> 6;
  int lane = threadIdx.x & 63;
  const float* p = Mb + (size_t)row * NN;
  float x[16]; float mx = -3.402823466e38f; float ax = 0.0f;
  float bm = -3.402823466e38f; int bi = 0;
  #pragma unroll
  for (int k = 0; k < 16; k++){
    x[k] = p[lane + 64 * k];
    mx = fmaxf(mx, x[k]);
    ax = fmaxf(ax, fabsf(x[k]));
    if (x[k] > bm){ bm = x[k]; bi = lane + 64 * k; }
  }
  mx = wmax(mx); ax = wmax(ax);
  #pragma unroll
  for (int o = 32; o > 0; o >>= 1){
    float om = __shfl_xor(bm, o, 64); int oi = __shfl_xor(bi, o, 64);
    if (om > bm || (om == bm && oi < bi)){ bm = om; bi = oi; }
  }
  float s = 0.0f;
  #pragma unroll
  for (int k = 0; k < 16; k++) s += expf(x[k] - mx);
  s = wsum(s);
  if (lane == 0){
    lse[row] = mx + logf(s);
    axs[wid] = ax;
    if (bi == (row & 1023)) atomicAdd(&accs[48 + (blockIdx.x & 15)], 1.0f);
  }
  __syncthreads();
  if (threadIdx.x == 0){
    float a = fmaxf(fmaxf(axs[0], axs[1]), fmaxf(axs[2], axs[3]));
    atomicMax((int*)&accs[64 + (blockIdx.x & 15)], __float_as_int(a));
  }
}

__global__ void k_scale(float* accs){
  if (threadIdx.x == 0){
    float g = 0.0f;
    for (int j = 0; j < 16; j++) g = fmaxf(g, accs[64 + j]);
    accs[80] = (g * INV_TAU * LOG2E) / 32766.0f;   // IQ2
  }
}

// ---- fva_half[z][b,n,c] = sum_{m in half z} exp(M[b,n,m]-lse1[b,n]) * f1[(b+1)&7][m][c]
__global__ __launch_bounds__(256) void k_fva(const float* __restrict__ Mb,
                                             const float* __restrict__ lse1,
                                             const float* __restrict__ f1,
                                             float* __restrict__ fva){
  __shared__ float Ps[64][36];
  __shared__ float Bs[64][128];
  int b = blockIdx.y;
  int z = blockIdx.z;
  int n0 = blockIdx.x * 32;
  int mbase = z * 512;
  const float* Mrow = Mb + (size_t)(b * NN + n0) * NN + mbase;
  const float* fa = f1 + (size_t)((b + 1) & 7) * NN * NC + (size_t)mbase * NC;
  const float* lseb = lse1 + b * NN + n0;
  float* fvaH = fva + (size_t)z * 1048576;
  int tid = threadIdx.x;
  int ty = tid >> 5, tx = tid & 31;
  float acc[4][4] = {};
  for (int mm = 0; mm < 512; mm += 64){
    #pragma unroll
    for (int i = 0; i < 2; i++){
      int t = tid + 256 * i;
      int r = t >> 4, m4 = t & 15;
      float l = lseb[r];
      float4 v = *(const float4*)(Mrow + (size_t)r * NN + mm + m4 * 4);
      Ps[m4*4+0][r] = expf(v.x - l); Ps[m4*4+1][r] = expf(v.y - l);
      Ps[m4*4+2][r] = expf(v.z - l); Ps[m4*4+3][r] = expf(v.w - l);
    }
    #pragma unroll
    for (int i = 0; i < 8; i++){
      int t = tid + 256 * i;
      int m = t >> 5, c4 = t & 31;
      *(float4*)&Bs[m][c4 * 4] = *(const float4*)(fa + (size_t)(mm + m) * NC + c4 * 4);
    }
    __syncthreads();
    #pragma unroll 8
    for (int m = 0; m < 64; m++){
      float4 a4 = *(const float4*)&Ps[m][ty * 4];
      float4 b4 = *(const float4*)&Bs[m][tx * 4];
      acc[0][0] += a4.x*b4.x; acc[0][1] += a4.x*b4.y; acc[0][2] += a4.x*b4.z; acc[0][3] += a4.x*b4.w;
      acc[1][0] += a4.y*b4.x; acc[1][1] += a4.y*b4.y; acc[1][2] += a4.y*b4.z; acc[1][3] += a4.y*b4.w;
      acc[2][0] += a4.z*b4.x; acc[2][1] += a4.z*b4.y; acc[2][2] += a4.z*b4.z; acc[2][3] += a4.z*b4.w;
      acc[3][0] += a4.w*b4.x; acc[3][1] += a4.w*b4.y; acc[3][2] += a4.w*b4.z; acc[3][3] += a4.w*b4.w;
    }
    __syncthreads();
  }
  #pragma unroll
  for (int i = 0; i < 4; i++){
    float4 o = make_float4(acc[i][0], acc[i][1], acc[i][2], acc[i][3]);
    *(float4*)(fvaH + ((size_t)(b * NN + n0 + ty * 4 + i)) * NC + tx * 4) = o;
  }
}

// ---- merge fva halves + bf16 hi/lo split
__global__ __launch_bounds__(256) void k_split(const float* __restrict__ A,
                                               const float* __restrict__ B,
                                               u16* __restrict__ H, u16* __restrict__ L){
  int g = blockIdx.x * 256 + threadIdx.x;   // 262144 threads x 4 elems
  float4 a = ((const float4*)A)[g];
  float4 b = ((const float4*)B)[g];
  float s[4] = { a.x + b.x, a.y + b.y, a.z + b.z, a.w + b.w };
  u16 h[4], l[4];
  #pragma unroll
  for (int k = 0; k < 4; k++){
    h[k] = f2bf(s[k]);
    l[k] = f2bf(s[k] - bf2f(h[k]));
  }
  uint2 hw, lw;
  hw.x = (unsigned)h[0] | ((unsigned)h[1] << 16); hw.y = (unsigned)h[2] | ((unsigned)h[3] << 16);
  lw.x = (unsigned)l[0] | ((unsigned)l[1] << 16); lw.y = (unsigned)l[2] | ((unsigned)l[3] << 16);
  ((uint2*)H)[g] = hw; ((uint2*)L)[g] = lw;
}

// ---- quantize L2 = M*INV_TAU*LOG2E to int16 + transposed copy
__global__ __launch_bounds__(256) void k_quant_t(const float* __restrict__ Mb,
                                                 const float* __restrict__ accs,
                                                 short* __restrict__ Q,
                                                 short* __restrict__ Qt){
  __shared__ float T[64][68];
  float KQ = (INV_TAU * LOG2E) / accs[80];
  int b = blockIdx.z; int n0 = blockIdx.y * 64, m0 = blockIdx.x * 64;
  const float* src = Mb + (size_t)b * NN * NN;
  int tid = threadIdx.x;
  #pragma unroll
  for (int i = 0; i < 4; i++){
    int t = tid + 256 * i; int r = t >> 4, c4 = t & 15;
    float4 v = *(const float4*)(src + (size_t)(n0 + r) * NN + m0 + c4 * 4);
    float q0 = rintf(v.x * KQ);
    float q1 = rintf(v.y * KQ);
    float q2 = rintf(v.z * KQ);
    float q3 = rintf(v.w * KQ);
    T[r][c4*4+0] = q0; T[r][c4*4+1] = q1; T[r][c4*4+2] = q2; T[r][c4*4+3] = q3;
    int2 w;
    w.x = ((int)q0 & 0xFFFF) | ((int)q1 << 16);
    w.y = ((int)q2 & 0xFFFF) | ((int)q3 << 16);
    *(int2*)(Q + ((size_t)(b * NN + n0 + r) * NN + m0 + c4 * 4)) = w;
  }
  __syncthreads();
  #pragma unroll
  for (int i = 0; i < 4; i++){
    int t = tid + 256 * i; int r = t >> 4, c4 = t & 15;
    float q0 = T[c4*4+0][r], q1 = T[c4*4+1][r], q2 = T[c4*4+2][r], q3 = T[c4*4+3][r];
    int2 w;
    w.x = ((int)q0 & 0xFFFF) | ((int)q1 << 16);
    w.y = ((int)q2 & 0xFFFF) | ((int)q3 << 16);
    *(int2*)(Qt + ((size_t)(b * NN + m0 + r) * NN + n0 + c4 * 4)) = w;
  }
}

// ---- sinkhorn half-pass (log2 domain, 1 row/wave, 2048 blocks = 32 waves/CU):
// out[i] = -LSE2_j(q[i,j]*IQ2 + in[j])   [round-6 version, measured 5.45us/pass]
__global__ __launch_bounds__(256) void k_pass(const short* __restrict__ Q,
                                              const float* __restrict__ invec,
                                              float* __restrict__ outvec,
                                              const float* __restrict__ accs){
  const float IQ2 = accs[80];
  int tid = threadIdx.x, wid = tid >> 6, lane = tid & 63;
  int row = blockIdx.x * 4 + wid;      // 2048 blocks
  int b = row >> 10;
  float hh[16];
  load16(invec + b * NN, lane, hh);
  const int4* qp = (const int4*)(Q + (size_t)row * NN);
  int4 wa = qp[lane], wb = qp[64 + lane];
  int qq[8] = { wa.x, wa.y, wa.z, wa.w, wb.x, wb.y, wb.z, wb.w };
  float x[16]; float mx = -3.402823466e38f;
  #pragma unroll
  for (int k = 0; k < 8; k++){
    x[2*k]   = fmaf((float)(short)(qq[k]), IQ2, hh[2*k]);
    x[2*k+1] = fmaf((float)(qq[k] >> 16),  IQ2, hh[2*k+1]);
    mx = fmaxf(mx, fmaxf(x[2*k], x[2*k+1]));
  }
  mx = wmax(mx);
  float s = 0.0f;
  #pragma unroll
  for (int k = 0; k < 16; k++) s += fexp2(x[k] - mx);
  s = wsum(s);
  if (lane == 0) outvec[row] = -(mx + flog2(s));
}

// ---- fused final reduction (log2 domain, pc in padded split LDS)
__global__ __launch_bounds__(1024) void k_final(const short* __restrict__ Q,
                                                const short* __restrict__ Q12,
                                                const float* __restrict__ lse2,
                                                const float* __restrict__ P2,
                                                const float* __restrict__ V2,
                                                const float* __restrict__ pc0,
                                                float* __restrict__ accs){
  __shared__ float pcx[1152], pcy[1152], pcz[1152];
  __shared__ float partial[3][16];
  const float IQ2 = accs[80];
  const float IQ12_2 = (400.0f / 32766.0f) * LOG2E;
  int tid = threadIdx.x, wid = tid >> 6, lane = tid & 63;
  int row = blockIdx.x * 16 + wid;     // grid 512
  int b = row >> 10, n = row & 1023;
  {
    int m = tid;
    const float* pg = pc0 + (size_t)b * 3072 + 3 * m;
    float px = pg[0], py = pg[1], pz = pg[2];
    int idx = m + (m >> 3);
    pcx[idx] = px; pcy[idx] = py; pcz[idx] = pz;
  }
  __syncthreads();
  const int4* qp  = (const int4*)(Q   + (size_t)row * NN);
  const int4* qp2 = (const int4*)(Q12 + (size_t)row * NN);
  int4 a1 = qp[lane],  b1 = qp[64 + lane];
  int4 a2 = qp2[lane], b2 = qp2[64 + lane];
  int q1[8] = { a1.x, a1.y, a1.z, a1.w, b1.x, b1.y, b1.z, b1.w };
  int q2[8] = { a2.x, a2.y, a2.z, a2.w, b2.x, b2.y, b2.z, b2.w };
  float L[16], c[16];
  float cmx = -3.402823466e38f;
  #pragma unroll
  for (int k = 0; k < 8; k++){
    L[2*k]   = (float)(short)(q1[k]) * IQ2;
    L[2*k+1] = (float)(q1[k] >> 16)  * IQ2;
    c[2*k]   = (float)(short)(q2[k]) * IQ12_2;
    c[2*k+1] = (float)(q2[k] >> 16)  * IQ12_2;
    cmx = fmaxf(cmx, fmaxf(c[2*k], c[2*k+1]));
  }
  cmx = wmax(cmx);
  float cs = 0.0f;
  #pragma unroll
  for (int k = 0; k < 16; k++) cs += fexp2(c[k] - cmx);
  cs = wsum(cs);
  float lse12r = cmx + flog2(cs);
  float vv[16];
  load16(V2 + b * NN, lane, vv);
  int nidx = n + (n >> 3);
  float qx = pcx[nidx], qy = pcy[nidx], qz = pcz[nidx];
  float c1row = -lse2[row] * LOG2E;
  float Prow = P2[row];
  float sl = 0.0f, slc = 0.0f, spi = 0.0f;
  #pragma unroll
  for (int k = 0; k < 16; k++){
    int m = (k < 8) ? (8 * lane + k) : (512 + 8 * lane + k - 8);
    int midx = m + (m >> 3);
    float e1 = fexp2(fmaf(L[k], 0.3f, c1row));
    float sk = fexp2(L[k] + Prow + vv[k]);
    float e2 = fexp2(c[k] - lse12r);
    float dx = qx - pcx[midx], dy = qy - pcy[midx], dz = qz - pcz[midx];
    float d = sqrtf(sqrtf(dx*dx + dy*dy + dz*dz));
    sl  += d * (e1 + e2);
    slc += fabsf(sk - e1);
    spi += fabsf(((m == n) ? 1.0f : 0.0f) - sk);
  }
  sl = wsum(sl); slc = wsum(slc); spi = wsum(spi);
  if (lane == 0){ partial[0][wid] = sl; partial[1][wid] = slc; partial[2][wid] = spi; }
  __syncthreads();
  if (tid < 3){
    float t = 0.0f;
    #pragma unroll
    for (int i = 0; i < 16; i++) t += partial[tid][i];
    atomicAdd(&accs[tid * 16 + (blockIdx.x & 15)], t);
  }
}

__global__ void k_finalize(const float* __restrict__ accs, float* __restrict__ out){
  if (threadIdx.x == 0){
    float sl = 0, slc = 0, spi = 0, scm = 0;
    for (int j = 0; j < 16; j++){
      sl += accs[j]; slc += accs[16 + j]; spi += accs[32 + j]; scm += accs[48 + j];
    }
    float loss = sl / 1024.0f;
    float Lc   = 3.0f * slc / 1024.0f;
    float perm = 3.0f * spi / 1024.0f;
    float total = loss + Lc;
    out[0] = total / 8.0f;
    out[1] = loss / 8.0f;
    out[2] = Lc / 8.0f;
    out[3] = scm / 8.0f;
    out[4] = perm / 8.0f;
  }
}

extern "C" void kernel_launch(void* const* d_in, const int* in_sizes, int n_in,
                              void* d_out, int out_size, void* d_ws, size_t ws_size,
                              hipStream_t stream){
  const float* feats = (const float*)d_in[0];   // [16,1024,128]
  const float* pc0   = (const float*)d_in[1];   // [8,1024,3]
  float* out = (float*)d_out;                   // 5 scalars

  float* ws   = (float*)d_ws;
  float* f1   = ws;                       // 1,048,576 f
  u16* f1h    = (u16*)(f1 + 1048576);     // 1,048,576 u16
  u16* f1l    = f1h + 1048576;
  u16* f2h    = f1l + 1048576;
  u16* f2l    = f2h + 1048576;
  u16* fvh    = f2l + 1048576;
  u16* fvl    = fvh + 1048576;
  float* fva  = (float*)(fvl + 1048576);  // 2,097,152 f (two halves)
  float* M    = fva + 2097152;            // 8,388,608 f
  short* Q    = (short*)(M + 8388608);    // 8,388,608 s16 (log2-scaled)
  short* Qt   = Q + 8388608;              // 8,388,608 s16 (later reused as Q12)
  float* lse1 = (float*)(Qt + 8388608);   // 8192
  float* lse2 = lse1 + 8192;
  float* P    = lse2 + 8192;
  float* V    = P + 8192;
  float* accs = V + 8192;                 // 160
  if (ws_size < (size_t)((char*)(accs + 160) - (char*)ws)) return;

  k_init<<<32, 256, 0, stream>>>(accs, P, V);
  k_normalize<<<16384, 64, 0, stream>>>(feats, f1, f1h, f1l, f2h, f2l);
  // corr_1a = f1 @ roll(f1)^T  (MFMA, hi/lo split)
  k_gemm_mfma<<<dim3(16,16,8), 256, 0, stream>>>(f1h, f1l, f1h, f1l, M, 1, 0);
  k_rowstats<<<2048, 256, 0, stream>>>(M, lse1);
  // f1_via_fa = softmax(corr_1a) @ roll(f1) — m-split x2 (vector)
  k_fva<<<dim3(32,8,2), 256, 0, stream>>>(M, lse1, f1, fva);
  k_split<<<1024, 256, 0, stream>>>(fva, fva + 1048576, fvh, fvl);
  // corr_1a2 = fva @ f2^T  (MFMA)
  k_gemm_mfma<<<dim3(16,16,8), 256, 0, stream>>>(fvh, fvl, f2h, f2l, M, 0, 0);
  k_rowstats_argmax<<<2048, 256, 0, stream>>>(M, lse2, accs);
  k_scale<<<1, 64, 0, stream>>>(accs);
  k_quant_t<<<dim3(16,16,8), 256, 0, stream>>>(M, accs, Q, Qt);
  // sinkhorn: 30 x (row pass -> P, col pass -> V), log2 domain
  for (int it = 0; it < 30; it++){
    k_pass<<<2048, 256, 0, stream>>>(Q,  V, P, accs);
    k_pass<<<2048, 256, 0, stream>>>(Qt, P, V, accs);
  }
  // corr_12 = f1 @ f2^T as int16 (MFMA), into the now-dead Qt buffer
  k_gemm_mfma<<<dim3(16,16,8), 256, 0, stream>>>(f1h, f1l, f2h, f2l, Qt, 0, 1);
  k_final<<<512, 1024, 0, stream>>>(Q, Qt, lse2, P, V, pc0, accs);
  k_finalize<<<1, 64, 0, stream>>>(accs, out);
}

// Round 9
// 478.722 us; speedup vs baseline: 1.3682x; 1.1226x over previous
//
#include <hip/hip_runtime.h>
#include <math.h>

#define NB 8
#define NN 1024
#define NC 128
#define INV_TAU (1.0f/0.3f)
#define LOG2E 1.44269504088896340736f

typedef unsigned short u16;
typedef short bf16x8 __attribute__((ext_vector_type(8)));
typedef float f32x4 __attribute__((ext_vector_type(4)));

__device__ __forceinline__ float wsum(float v){
  #pragma unroll
  for (int o = 32; o > 0; o >>= 1) v += __shfl_xor(v, o, 64);
  return v;
}
__device__ __forceinline__ float wmax(float v){
  #pragma unroll
  for (int o = 32; o > 0; o >>= 1) v = fmaxf(v, __shfl_xor(v, o, 64));
  return v;
}
__device__ __forceinline__ float fexp2(float x){ return __builtin_amdgcn_exp2f(x); }
__device__ __forceinline__ float flog2(float x){ return __builtin_amdgcn_logf(x); }
__device__ __forceinline__ u16 f2bf(float f){     // RNE bf16, any finite sign
  unsigned u = __float_as_uint(f);
  return (u16)((u + 0x7FFFu + ((u >> 16) & 1u)) >> 16);
}
__device__ __forceinline__ float bf2f(u16 h){ return __uint_as_float((unsigned)h << 16); }

__device__ __forceinline__ void load16(const float* __restrict__ base, int lane, float* o){
  float4 a = *(const float4*)(base + 8 * lane);
  float4 b = *(const float4*)(base + 8 * lane + 4);
  float4 c = *(const float4*)(base + 512 + 8 * lane);
  float4 d = *(const float4*)(base + 512 + 8 * lane + 4);
  o[0]=a.x; o[1]=a.y; o[2]=a.z; o[3]=a.w; o[4]=b.x; o[5]=b.y; o[6]=b.z; o[7]=b.w;
  o[8]=c.x; o[9]=c.y; o[10]=c.z; o[11]=c.w; o[12]=d.x; o[13]=d.y; o[14]=d.z; o[15]=d.w;
}

// accs: [0:16) loss | [16:32) lc | [32:48) perm | [48:64) cm | [64:80) gmax | 80 IQ2
__global__ void k_init(float* accs, float* P, float* V){
  int i = blockIdx.x * 256 + threadIdx.x;   // 8192 threads
  if (i < 160) accs[i] = 0.0f;
  P[i] = 0.0f; V[i] = 0.0f;
}

// ---- L2 normalize * 20; emit f1 fp32 (for k_fva) + hi/lo bf16 splits of f1,f2
__global__ void k_normalize(const float* __restrict__ feats, float* __restrict__ f1,
                            u16* __restrict__ f1h, u16* __restrict__ f1l,
                            u16* __restrict__ f2h, u16* __restrict__ f2l){
  int vid = blockIdx.x;
  int lane = threadIdx.x;          // 64 threads, 2 floats each
  const float* src = feats + (size_t)vid * NC;
  float2 x = *(const float2*)(src + lane * 2);
  float s = wsum(x.x * x.x + x.y * x.y);
  float sc = 20.0f / fmaxf(sqrtf(s), 1e-12f);
  int batch = vid >> 10, n = vid & 1023;
  size_t off = ((size_t)(batch >> 1) * NN + n) * NC + 2 * lane;
  float2 y; y.x = x.x * sc; y.y = x.y * sc;
  u16 h0 = f2bf(y.x), h1 = f2bf(y.y);
  u16 l0 = f2bf(y.x - bf2f(h0)), l1 = f2bf(y.y - bf2f(h1));
  unsigned hw = (unsigned)h0 | ((unsigned)h1 << 16);
  unsigned lw = (unsigned)l0 | ((unsigned)l1 << 16);
  if (batch & 1){
    *(unsigned*)(f2h + off) = hw; *(unsigned*)(f2l + off) = lw;
  } else {
    *(float2*)(f1 + off) = y;
    *(unsigned*)(f1h + off) = hw; *(unsigned*)(f1l + off) = lw;
  }
}

// ---- MFMA GEMM v2 (LDS-staged, 128x128 tile): C[b][n][m] = sum_k A[b][n][k]*B[(b+rollB)&7][m][k]
// hi/lo bf16 splits, 3 cross terms. XOR-swizzled LDS (16B unit ^ (row&7)) - conflict-free.
__global__ __launch_bounds__(256) void k_gemm_mfma(const u16* __restrict__ Ah_g,
                                                   const u16* __restrict__ Al_g,
                                                   const u16* __restrict__ Bh_g,
                                                   const u16* __restrict__ Bl_g,
                                                   void* __restrict__ Cm,
                                                   int rollB, int q16){
  __shared__ __align__(16) u16 As_h[128][64];   // 16 KB each, 64 KB total
  __shared__ __align__(16) u16 As_l[128][64];
  __shared__ __align__(16) u16 Bs_h[128][64];
  __shared__ __align__(16) u16 Bs_l[128][64];
  const float QS12 = 32766.0f / 400.0f;
  int b = blockIdx.z;
  int m0 = blockIdx.x * 128, n0 = blockIdx.y * 128;
  int tid = threadIdx.x, w = tid >> 6, lane = tid & 63;
  int quad = lane >> 4, l15 = lane & 15;
  int wn = (w >> 1) * 64, wm = (w & 1) * 64;
  size_t abase = (size_t)b * NN * NC;
  size_t bbase = (size_t)((b + rollB) & 7) * NN * NC;
  f32x4 z = {0.0f, 0.0f, 0.0f, 0.0f};
  f32x4 acc[4][4] = {{z,z,z,z},{z,z,z,z},{z,z,z,z},{z,z,z,z}};
  for (int kk = 0; kk < NC; kk += 64){
    // stage 128 rows x 64 k of all 4 operands; 16B units, coalesced
    #pragma unroll
    for (int i2 = 0; i2 < 4; i2++){
      int uidx = tid + 256 * i2;          // 0..1023
      int r = uidx >> 3, u = uidx & 7;
      int su = ((u ^ (r & 7)) << 3);
      size_t goA = abase + (size_t)(n0 + r) * NC + kk + u * 8;
      size_t goB = bbase + (size_t)(m0 + r) * NC + kk + u * 8;
      *(uint4*)&As_h[r][su] = *(const uint4*)(Ah_g + goA);
      *(uint4*)&As_l[r][su] = *(const uint4*)(Al_g + goA);
      *(uint4*)&Bs_h[r][su] = *(const uint4*)(Bh_g + goB);
      *(uint4*)&Bs_l[r][su] = *(const uint4*)(Bl_g + goB);
    }
    __syncthreads();
    #pragma unroll
    for (int c = 0; c < 2; c++){          // two K32 chunks per stage
      bf16x8 ah[4], al[4], bh[4], bl[4];
      #pragma unroll
      for (int i = 0; i < 4; i++){
        int rn = wn + i * 16 + l15;
        int sn = (((c * 4 + quad) ^ (rn & 7)) << 3);
        ah[i] = *(const bf16x8*)&As_h[rn][sn];
        al[i] = *(const bf16x8*)&As_l[rn][sn];
        int rm = wm + i * 16 + l15;
        int sm = (((c * 4 + quad) ^ (rm & 7)) << 3);
        bh[i] = *(const bf16x8*)&Bs_h[rm][sm];
        bl[i] = *(const bf16x8*)&Bs_l[rm][sm];
      }
      #pragma unroll
      for (int i = 0; i < 4; i++)
        #pragma unroll
        for (int j = 0; j < 4; j++){
          acc[i][j] = __builtin_amdgcn_mfma_f32_16x16x32_bf16(ah[i], bh[j], acc[i][j], 0, 0, 0);
          acc[i][j] = __builtin_amdgcn_mfma_f32_16x16x32_bf16(ah[i], bl[j], acc[i][j], 0, 0, 0);
          acc[i][j] = __builtin_amdgcn_mfma_f32_16x16x32_bf16(al[i], bh[j], acc[i][j], 0, 0, 0);
        }
    }
    __syncthreads();
  }
  // C/D layout per 16x16: row(n) = quad*4 + r, col(m) = l15  [verified round 7, absmax 0]
  if (q16){
    short* Cb = (short*)Cm + (size_t)b * NN * NN;
    #pragma unroll
    for (int i = 0; i < 4; i++)
      #pragma unroll
      for (int j = 0; j < 4; j++)
        #pragma unroll
        for (int r = 0; r < 4; r++){
          int n = n0 + wn + i * 16 + quad * 4 + r;
          int m = m0 + wm + j * 16 + l15;
          float q = rintf(fminf(fmaxf(acc[i][j][r] * QS12, -32766.0f), 32766.0f));
          Cb[(size_t)n * NN + m] = (short)(int)q;
        }
  } else {
    float* Cb = (float*)Cm + (size_t)b * NN * NN;
    #pragma unroll
    for (int i = 0; i < 4; i++)
      #pragma unroll
      for (int j = 0; j < 4; j++)
        #pragma unroll
        for (int r = 0; r < 4; r++){
          int n = n0 + wn + i * 16 + quad * 4 + r;
          int m = m0 + wm + j * 16 + l15;
          Cb[(size_t)n * NN + m] = acc[i][j][r];
        }
  }
}

// ---- per-row logsumexp (nat domain, for k_fva)
__global__ void k_rowstats(const float* __restrict__ Mb, float* __restrict__ lse){
  int row = blockIdx.x * 4 + (threadIdx.x >> 6);
  int lane = threadIdx.x & 63;
  const float* p = Mb + (size_t)row * NN;
  float x[16]; float mx = -3.402823466e38f;
  #pragma unroll
  for (int k = 0; k < 16; k++){ x[k] = p[lane + 64 * k]; mx = fmaxf(mx, x[k]); }
  mx = wmax(mx);
  float s = 0.0f;
  #pragma unroll
  for (int k = 0; k < 16; k++) s += expf(x[k] - mx);
  s = wsum(s);
  if (lane == 0) lse[row] = mx + logf(s);
}

// ---- row stats (nat) + argmax + correct_match + global absmax
__global__ void k_rowstats_argmax(const float* __restrict__ Mb, float* __restrict__ lse,
                                  float* __restrict__ accs){
  __shared__ float axs[4];
  int row = blockIdx.x * 4 + (threadIdx.x >> 6);
  int wid = threadIdx.x >> 6;
  int lane = threadIdx.x & 63;
  const float* p = Mb + (size_t)row * NN;
  float x[16]; float mx = -3.402823466e38f; float ax = 0.0f;
  float bm = -3.402823466e38f; int bi = 0;
  #pragma unroll
  for (int k = 0; k < 16; k++){
    x[k] = p[lane + 64 * k];
    mx = fmaxf(mx, x[k]);
    ax = fmaxf(ax, fabsf(x[k]));
    if (x[k] > bm){ bm = x[k]; bi = lane + 64 * k; }
  }
  mx = wmax(mx); ax = wmax(ax);
  #pragma unroll
  for (int o = 32; o > 0; o >>= 1){
    float om = __shfl_xor(bm, o, 64); int oi = __shfl_xor(bi, o, 64);
    if (om > bm || (om == bm && oi < bi)){ bm = om; bi = oi; }
  }
  float s = 0.0f;
  #pragma unroll
  for (int k = 0; k < 16; k++) s += expf(x[k] - mx);
  s = wsum(s);
  if (lane == 0){
    lse[row] = mx + logf(s);
    axs[wid] = ax;
    if (bi == (row & 1023)) atomicAdd(&accs[48 + (blockIdx.x & 15)], 1.0f);
  }
  __syncthreads();
  if (threadIdx.x == 0){
    float a = fmaxf(fmaxf(axs[0], axs[1]), fmaxf(axs[2], axs[3]));
    atomicMax((int*)&accs[64 + (blockIdx.x & 15)], __float_as_int(a));
  }
}

__global__ void k_scale(float* accs){
  if (threadIdx.x == 0){
    float g = 0.0f;
    for (int j = 0; j < 16; j++) g = fmaxf(g, accs[64 + j]);
    accs[80] = (g * INV_TAU * LOG2E) / 32766.0f;   // IQ2
  }
}

// ---- fva_half[z][b,n,c] = sum_{m in half z} exp(M[b,n,m]-lse1[b,n]) * f1[(b+1)&7][m][c]
__global__ __launch_bounds__(256) void k_fva(const float* __restrict__ Mb,
                                             const float* __restrict__ lse1,
                                             const float* __restrict__ f1,
                                             float* __restrict__ fva){
  __shared__ float Ps[64][36];
  __shared__ float Bs[64][128];
  int b = blockIdx.y;
  int z = blockIdx.z;
  int n0 = blockIdx.x * 32;
  int mbase = z * 512;
  const float* Mrow = Mb + (size_t)(b * NN + n0) * NN + mbase;
  const float* fa = f1 + (size_t)((b + 1) & 7) * NN * NC + (size_t)mbase * NC;
  const float* lseb = lse1 + b * NN + n0;
  float* fvaH = fva + (size_t)z * 1048576;
  int tid = threadIdx.x;
  int ty = tid >> 5, tx = tid & 31;
  float acc[4][4] = {};
  for (int mm = 0; mm < 512; mm += 64){
    #pragma unroll
    for (int i = 0; i < 2; i++){
      int t = tid + 256 * i;
      int r = t >> 4, m4 = t & 15;
      float l = lseb[r];
      float4 v = *(const float4*)(Mrow + (size_t)r * NN + mm + m4 * 4);
      Ps[m4*4+0][r] = expf(v.x - l); Ps[m4*4+1][r] = expf(v.y - l);
      Ps[m4*4+2][r] = expf(v.z - l); Ps[m4*4+3][r] = expf(v.w - l);
    }
    #pragma unroll
    for (int i = 0; i < 8; i++){
      int t = tid + 256 * i;
      int m = t >> 5, c4 = t & 31;
      *(float4*)&Bs[m][c4 * 4] = *(const float4*)(fa + (size_t)(mm + m) * NC + c4 * 4);
    }
    __syncthreads();
    #pragma unroll 8
    for (int m = 0; m < 64; m++){
      float4 a4 = *(const float4*)&Ps[m][ty * 4];
      float4 b4 = *(const float4*)&Bs[m][tx * 4];
      acc[0][0] += a4.x*b4.x; acc[0][1] += a4.x*b4.y; acc[0][2] += a4.x*b4.z; acc[0][3] += a4.x*b4.w;
      acc[1][0] += a4.y*b4.x; acc[1][1] += a4.y*b4.y; acc[1][2] += a4.y*b4.z; acc[1][3] += a4.y*b4.w;
      acc[2][0] += a4.z*b4.x; acc[2][1] += a4.z*b4.y; acc[2][2] += a4.z*b4.z; acc[2][3] += a4.z*b4.w;
      acc[3][0] += a4.w*b4.x; acc[3][1] += a4.w*b4.y; acc[3][2] += a4.w*b4.z; acc[3][3] += a4.w*b4.w;
    }
    __syncthreads();
  }
  #pragma unroll
  for (int i = 0; i < 4; i++){
    float4 o = make_float4(acc[i][0], acc[i][1], acc[i][2], acc[i][3]);
    *(float4*)(fvaH + ((size_t)(b * NN + n0 + ty * 4 + i)) * NC + tx * 4) = o;
  }
}

// ---- merge fva halves + bf16 hi/lo split
__global__ __launch_bounds__(256) void k_split(const float* __restrict__ A,
                                               const float* __restrict__ B,
                                               u16* __restrict__ H, u16* __restrict__ L){
  int g = blockIdx.x * 256 + threadIdx.x;   // 262144 threads x 4 elems
  float4 a = ((const float4*)A)[g];
  float4 b = ((const float4*)B)[g];
  float s[4] = { a.x + b.x, a.y + b.y, a.z + b.z, a.w + b.w };
  u16 h[4], l[4];
  #pragma unroll
  for (int k = 0; k < 4; k++){
    h[k] = f2bf(s[k]);
    l[k] = f2bf(s[k] - bf2f(h[k]));
  }
  uint2 hw, lw;
  hw.x = (unsigned)h[0] | ((unsigned)h[1] << 16); hw.y = (unsigned)h[2] | ((unsigned)h[3] << 16);
  lw.x = (unsigned)l[0] | ((unsigned)l[1] << 16); lw.y = (unsigned)l[2] | ((unsigned)l[3] << 16);
  ((uint2*)H)[g] = hw; ((uint2*)L)[g] = lw;
}

// ---- quantize L2 = M*INV_TAU*LOG2E to int16 + transposed copy
__global__ __launch_bounds__(256) void k_quant_t(const float* __restrict__ Mb,
                                                 const float* __restrict__ accs,
                                                 short* __restrict__ Q,
                                                 short* __restrict__ Qt){
  __shared__ float T[64][68];
  float KQ = (INV_TAU * LOG2E) / accs[80];
  int b = blockIdx.z; int n0 = blockIdx.y * 64, m0 = blockIdx.x * 64;
  const float* src = Mb + (size_t)b * NN * NN;
  int tid = threadIdx.x;
  #pragma unroll
  for (int i = 0; i < 4; i++){
    int t = tid + 256 * i; int r = t >> 4, c4 = t & 15;
    float4 v = *(const float4*)(src + (size_t)(n0 + r) * NN + m0 + c4 * 4);
    float q0 = rintf(v.x * KQ);
    float q1 = rintf(v.y * KQ);
    float q2 = rintf(v.z * KQ);
    float q3 = rintf(v.w * KQ);
    T[r][c4*4+0] = q0; T[r][c4*4+1] = q1; T[r][c4*4+2] = q2; T[r][c4*4+3] = q3;
    int2 w;
    w.x = ((int)q0 & 0xFFFF) | ((int)q1 << 16);
    w.y = ((int)q2 & 0xFFFF) | ((int)q3 << 16);
    *(int2*)(Q + ((size_t)(b * NN + n0 + r) * NN + m0 + c4 * 4)) = w;
  }
  __syncthreads();
  #pragma unroll
  for (int i = 0; i < 4; i++){
    int t = tid + 256 * i; int r = t >> 4, c4 = t & 15;
    float q0 = T[c4*4+0][r], q1 = T[c4*4+1][r], q2 = T[c4*4+2][r], q3 = T[c4*4+3][r];
    int2 w;
    w.x = ((int)q0 & 0xFFFF) | ((int)q1 << 16);
    w.y = ((int)q2 & 0xFFFF) | ((int)q3 << 16);
    *(int2*)(Qt + ((size_t)(b * NN + m0 + r) * NN + n0 + c4 * 4)) = w;
  }
}

// ---- sinkhorn half-pass (log2 domain, 1 row/wave, 2048 blocks = 32 waves/CU)
__global__ __launch_bounds__(256) void k_pass(const short* __restrict__ Q,
                                              const float* __restrict__ invec,
                                              float* __restrict__ outvec,
                                              const float* __restrict__ accs){
  const float IQ2 = accs[80];
  int tid = threadIdx.x, wid = tid >> 6, lane = tid & 63;
  int row = blockIdx.x * 4 + wid;      // 2048 blocks
  int b = row >> 10;
  float hh[16];
  load16(invec + b * NN, lane, hh);
  const int4* qp = (const int4*)(Q + (size_t)row * NN);
  int4 wa = qp[lane], wb = qp[64 + lane];
  int qq[8] = { wa.x, wa.y, wa.z, wa.w, wb.x, wb.y, wb.z, wb.w };
  float x[16]; float mx = -3.402823466e38f;
  #pragma unroll
  for (int k = 0; k < 8; k++){
    x[2*k]   = fmaf((float)(short)(qq[k]), IQ2, hh[2*k]);
    x[2*k+1] = fmaf((float)(qq[k] >> 16),  IQ2, hh[2*k+1]);
    mx = fmaxf(mx, fmaxf(x[2*k], x[2*k+1]));
  }
  mx = wmax(mx);
  float s = 0.0f;
  #pragma unroll
  for (int k = 0; k < 16; k++) s += fexp2(x[k] - mx);
  s = wsum(s);
  if (lane == 0) outvec[row] = -(mx + flog2(s));
}

// ---- fused final reduction (log2 domain, pc in padded split LDS)
__global__ __launch_bounds__(1024) void k_final(const short* __restrict__ Q,
                                                const short* __restrict__ Q12,
                                                const float* __restrict__ lse2,
                                                const float* __restrict__ P2,
                                                const float* __restrict__ V2,
                                                const float* __restrict__ pc0,
                                                float* __restrict__ accs){
  __shared__ float pcx[1152], pcy[1152], pcz[1152];
  __shared__ float partial[3][16];
  const float IQ2 = accs[80];
  const float IQ12_2 = (400.0f / 32766.0f) * LOG2E;
  int tid = threadIdx.x, wid = tid >> 6, lane = tid & 63;
  int row = blockIdx.x * 16 + wid;     // grid 512
  int b = row >> 10, n = row & 1023;
  {
    int m = tid;
    const float* pg = pc0 + (size_t)b * 3072 + 3 * m;
    float px = pg[0], py = pg[1], pz = pg[2];
    int idx = m + (m >> 3);
    pcx[idx] = px; pcy[idx] = py; pcz[idx] = pz;
  }
  __syncthreads();
  const int4* qp  = (const int4*)(Q   + (size_t)row * NN);
  const int4* qp2 = (const int4*)(Q12 + (size_t)row * NN);
  int4 a1 = qp[lane],  b1 = qp[64 + lane];
  int4 a2 = qp2[lane], b2 = qp2[64 + lane];
  int q1[8] = { a1.x, a1.y, a1.z, a1.w, b1.x, b1.y, b1.z, b1.w };
  int q2[8] = { a2.x, a2.y, a2.z, a2.w, b2.x, b2.y, b2.z, b2.w };
  float L[16], c[16];
  float cmx = -3.402823466e38f;
  #pragma unroll
  for (int k = 0; k < 8; k++){
    L[2*k]   = (float)(short)(q1[k]) * IQ2;
    L[2*k+1] = (float)(q1[k] >> 16)  * IQ2;
    c[2*k]   = (float)(short)(q2[k]) * IQ12_2;
    c[2*k+1] = (float)(q2[k] >> 16)  * IQ12_2;
    cmx = fmaxf(cmx, fmaxf(c[2*k], c[2*k+1]));
  }
  cmx = wmax(cmx);
  float cs = 0.0f;
  #pragma unroll
  for (int k = 0; k < 16; k++) cs += fexp2(c[k] - cmx);
  cs = wsum(cs);
  float lse12r = cmx + flog2(cs);
  float vv[16];
  load16(V2 + b * NN, lane, vv);
  int nidx = n + (n >> 3);
  float qx = pcx[nidx], qy = pcy[nidx], qz = pcz[nidx];
  float c1row = -lse2[row] * LOG2E;
  float Prow = P2[row];
  float sl = 0.0f, slc = 0.0f, spi = 0.0f;
  #pragma unroll
  for (int k = 0; k < 16; k++){
    int m = (k < 8) ? (8 * lane + k) : (512 + 8 * lane + k - 8);
    int midx = m + (m >> 3);
    float e1 = fexp2(fmaf(L[k], 0.3f, c1row));
    float sk = fexp2(L[k] + Prow + vv[k]);
    float e2 = fexp2(c[k] - lse12r);
    float dx = qx - pcx[midx], dy = qy - pcy[midx], dz = qz - pcz[midx];
    float d = sqrtf(sqrtf(dx*dx + dy*dy + dz*dz));
    sl  += d * (e1 + e2);
    slc += fabsf(sk - e1);
    spi += fabsf(((m == n) ? 1.0f : 0.0f) - sk);
  }
  sl = wsum(sl); slc = wsum(slc); spi = wsum(spi);
  if (lane == 0){ partial[0][wid] = sl; partial[1][wid] = slc; partial[2][wid] = spi; }
  __syncthreads();
  if (tid < 3){
    float t = 0.0f;
    #pragma unroll
    for (int i = 0; i < 16; i++) t += partial[tid][i];
    atomicAdd(&accs[tid * 16 + (blockIdx.x & 15)], t);
  }
}

__global__ void k_finalize(const float* __restrict__ accs, float* __restrict__ out){
  if (threadIdx.x == 0){
    float sl = 0, slc = 0, spi = 0, scm = 0;
    for (int j = 0; j < 16; j++){
      sl += accs[j]; slc += accs[16 + j]; spi += accs[32 + j]; scm += accs[48 + j];
    }
    float loss = sl / 1024.0f;
    float Lc   = 3.0f * slc / 1024.0f;
    float perm = 3.0f * spi / 1024.0f;
    float total = loss + Lc;
    out[0] = total / 8.0f;
    out[1] = loss / 8.0f;
    out[2] = Lc / 8.0f;
    out[3] = scm / 8.0f;
    out[4] = perm / 8.0f;
  }
}

extern "C" void kernel_launch(void* const* d_in, const int* in_sizes, int n_in,
                              void* d_out, int out_size, void* d_ws, size_t ws_size,
                              hipStream_t stream){
  const float* feats = (const float*)d_in[0];   // [16,1024,128]
  const float* pc0   = (const float*)d_in[1];   // [8,1024,3]
  float* out = (float*)d_out;                   // 5 scalars

  float* ws   = (float*)d_ws;
  float* f1   = ws;                       // 1,048,576 f
  u16* f1h    = (u16*)(f1 + 1048576);     // 1,048,576 u16
  u16* f1l    = f1h + 1048576;
  u16* f2h    = f1l + 1048576;
  u16* f2l    = f2h + 1048576;
  u16* fvh    = f2l + 1048576;
  u16* fvl    = fvh + 1048576;
  float* fva  = (float*)(fvl + 1048576);  // 2,097,152 f (two halves)
  float* M    = fva + 2097152;            // 8,388,608 f
  short* Q    = (short*)(M + 8388608);    // 8,388,608 s16 (log2-scaled)
  short* Qt   = Q + 8388608;              // 8,388,608 s16 (later reused as Q12)
  float* lse1 = (float*)(Qt + 8388608);   // 8192
  float* lse2 = lse1 + 8192;
  float* P    = lse2 + 8192;
  float* V    = P + 8192;
  float* accs = V + 8192;                 // 160
  if (ws_size < (size_t)((char*)(accs + 160) - (char*)ws)) return;

  k_init<<<32, 256, 0, stream>>>(accs, P, V);
  k_normalize<<<16384, 64, 0, stream>>>(feats, f1, f1h, f1l, f2h, f2l);
  // corr_1a = f1 @ roll(f1)^T  (MFMA v2, LDS-staged)
  k_gemm_mfma<<<dim3(8,8,8), 256, 0, stream>>>(f1h, f1l, f1h, f1l, M, 1, 0);
  k_rowstats<<<2048, 256, 0, stream>>>(M, lse1);
  // f1_via_fa = softmax(corr_1a) @ roll(f1) — m-split x2 (vector)
  k_fva<<<dim3(32,8,2), 256, 0, stream>>>(M, lse1, f1, fva);
  k_split<<<1024, 256, 0, stream>>>(fva, fva + 1048576, fvh, fvl);
  // corr_1a2 = fva @ f2^T  (MFMA v2)
  k_gemm_mfma<<<dim3(8,8,8), 256, 0, stream>>>(fvh, fvl, f2h, f2l, M, 0, 0);
  k_rowstats_argmax<<<2048, 256, 0, stream>>>(M, lse2, accs);
  k_scale<<<1, 64, 0, stream>>>(accs);
  k_quant_t<<<dim3(16,16,8), 256, 0, stream>>>(M, accs, Q, Qt);
  // sinkhorn: 30 x (row pass -> P, col pass -> V), log2 domain
  for (int it = 0; it < 30; it++){
    k_pass<<<2048, 256, 0, stream>>>(Q,  V, P, accs);
    k_pass<<<2048, 256, 0, stream>>>(Qt, P, V, accs);
  }
  // corr_12 = f1 @ f2^T as int16 (MFMA v2), into the now-dead Qt buffer
  k_gemm_mfma<<<dim3(8,8,8), 256, 0, stream>>>(f1h, f1l, f2h, f2l, Qt, 0, 1);
  k_final<<<512, 1024, 0, stream>>>(Q, Qt, lse2, P, V, pc0, accs);
  k_finalize<<<1, 64, 0, stream>>>(accs, out);
}

// Round 10
// 474.750 us; speedup vs baseline: 1.3796x; 1.0084x over previous
//
#include <hip/hip_runtime.h>
#include <math.h>

#define NB 8
#define NN 1024
#define NC 128
#define INV_TAU (1.0f/0.3f)
#define LOG2E 1.44269504088896340736f

typedef unsigned short u16;
typedef short bf16x8 __attribute__((ext_vector_type(8)));
typedef float f32x4 __attribute__((ext_vector_type(4)));

__device__ __forceinline__ float wsum(float v){
  #pragma unroll
  for (int o = 32; o > 0; o >>= 1) v += __shfl_xor(v, o, 64);
  return v;
}
__device__ __forceinline__ float wmax(float v){
  #pragma unroll
  for (int o = 32; o > 0; o >>= 1) v = fmaxf(v, __shfl_xor(v, o, 64));
  return v;
}
__device__ __forceinline__ float fexp2(float x){ return __builtin_amdgcn_exp2f(x); }
__device__ __forceinline__ float flog2(float x){ return __builtin_amdgcn_logf(x); }
__device__ __forceinline__ u16 f2bf(float f){     // RNE bf16, any finite sign
  unsigned u = __float_as_uint(f);
  return (u16)((u + 0x7FFFu + ((u >> 16) & 1u)) >> 16);
}
__device__ __forceinline__ float bf2f(u16 h){ return __uint_as_float((unsigned)h << 16); }

__device__ __forceinline__ void load16(const float* __restrict__ base, int lane, float* o){
  float4 a = *(const float4*)(base + 8 * lane);
  float4 b = *(const float4*)(base + 8 * lane + 4);
  float4 c = *(const float4*)(base + 512 + 8 * lane);
  float4 d = *(const float4*)(base + 512 + 8 * lane + 4);
  o[0]=a.x; o[1]=a.y; o[2]=a.z; o[3]=a.w; o[4]=b.x; o[5]=b.y; o[6]=b.z; o[7]=b.w;
  o[8]=c.x; o[9]=c.y; o[10]=c.z; o[11]=c.w; o[12]=d.x; o[13]=d.y; o[14]=d.z; o[15]=d.w;
}

// accs: [0:16) loss | [16:32) lc | [32:48) perm | [48:64) cm | [64:80) gmax | 80 IQ2
__global__ void k_init(float* accs, float* P, float* V){
  int i = blockIdx.x * 256 + threadIdx.x;   // 8192 threads
  if (i < 160) accs[i] = 0.0f;
  P[i] = 0.0f; V[i] = 0.0f;
}

// ---- L2 normalize * 20; emit f1 fp32 (for k_fva) + hi/lo bf16 splits of f1,f2
__global__ void k_normalize(const float* __restrict__ feats, float* __restrict__ f1,
                            u16* __restrict__ f1h, u16* __restrict__ f1l,
                            u16* __restrict__ f2h, u16* __restrict__ f2l){
  int vid = blockIdx.x;
  int lane = threadIdx.x;          // 64 threads, 2 floats each
  const float* src = feats + (size_t)vid * NC;
  float2 x = *(const float2*)(src + lane * 2);
  float s = wsum(x.x * x.x + x.y * x.y);
  float sc = 20.0f / fmaxf(sqrtf(s), 1e-12f);
  int batch = vid >> 10, n = vid & 1023;
  size_t off = ((size_t)(batch >> 1) * NN + n) * NC + 2 * lane;
  float2 y; y.x = x.x * sc; y.y = x.y * sc;
  u16 h0 = f2bf(y.x), h1 = f2bf(y.y);
  u16 l0 = f2bf(y.x - bf2f(h0)), l1 = f2bf(y.y - bf2f(h1));
  unsigned hw = (unsigned)h0 | ((unsigned)h1 << 16);
  unsigned lw = (unsigned)l0 | ((unsigned)l1 << 16);
  if (batch & 1){
    *(unsigned*)(f2h + off) = hw; *(unsigned*)(f2l + off) = lw;
  } else {
    *(float2*)(f1 + off) = y;
    *(unsigned*)(f1h + off) = hw; *(unsigned*)(f1l + off) = lw;
  }
}

// ---- MFMA GEMM v2 (LDS-staged, 128x128 tile): C[b][n][m] = sum_k A[b][n][k]*B[(b+rollB)&7][m][k]
// hi/lo bf16 splits, 3 cross terms. XOR-swizzled LDS (16B unit ^ (row&7)) - conflict-free.
__global__ __launch_bounds__(256) void k_gemm_mfma(const u16* __restrict__ Ah_g,
                                                   const u16* __restrict__ Al_g,
                                                   const u16* __restrict__ Bh_g,
                                                   const u16* __restrict__ Bl_g,
                                                   void* __restrict__ Cm,
                                                   int rollB, int q16){
  __shared__ __align__(16) u16 As_h[128][64];   // 16 KB each, 64 KB total
  __shared__ __align__(16) u16 As_l[128][64];
  __shared__ __align__(16) u16 Bs_h[128][64];
  __shared__ __align__(16) u16 Bs_l[128][64];
  const float QS12 = 32766.0f / 400.0f;
  int b = blockIdx.z;
  int m0 = blockIdx.x * 128, n0 = blockIdx.y * 128;
  int tid = threadIdx.x, w = tid >> 6, lane = tid & 63;
  int quad = lane >> 4, l15 = lane & 15;
  int wn = (w >> 1) * 64, wm = (w & 1) * 64;
  size_t abase = (size_t)b * NN * NC;
  size_t bbase = (size_t)((b + rollB) & 7) * NN * NC;
  f32x4 z = {0.0f, 0.0f, 0.0f, 0.0f};
  f32x4 acc[4][4] = {{z,z,z,z},{z,z,z,z},{z,z,z,z},{z,z,z,z}};
  for (int kk = 0; kk < NC; kk += 64){
    #pragma unroll
    for (int i2 = 0; i2 < 4; i2++){
      int uidx = tid + 256 * i2;          // 0..1023
      int r = uidx >> 3, u = uidx & 7;
      int su = ((u ^ (r & 7)) << 3);
      size_t goA = abase + (size_t)(n0 + r) * NC + kk + u * 8;
      size_t goB = bbase + (size_t)(m0 + r) * NC + kk + u * 8;
      *(uint4*)&As_h[r][su] = *(const uint4*)(Ah_g + goA);
      *(uint4*)&As_l[r][su] = *(const uint4*)(Al_g + goA);
      *(uint4*)&Bs_h[r][su] = *(const uint4*)(Bh_g + goB);
      *(uint4*)&Bs_l[r][su] = *(const uint4*)(Bl_g + goB);
    }
    __syncthreads();
    #pragma unroll
    for (int c = 0; c < 2; c++){          // two K32 chunks per stage
      bf16x8 ah[4], al[4], bh[4], bl[4];
      #pragma unroll
      for (int i = 0; i < 4; i++){
        int rn = wn + i * 16 + l15;
        int sn = (((c * 4 + quad) ^ (rn & 7)) << 3);
        ah[i] = *(const bf16x8*)&As_h[rn][sn];
        al[i] = *(const bf16x8*)&As_l[rn][sn];
        int rm = wm + i * 16 + l15;
        int sm = (((c * 4 + quad) ^ (rm & 7)) << 3);
        bh[i] = *(const bf16x8*)&Bs_h[rm][sm];
        bl[i] = *(const bf16x8*)&Bs_l[rm][sm];
      }
      #pragma unroll
      for (int i = 0; i < 4; i++)
        #pragma unroll
        for (int j = 0; j < 4; j++){
          acc[i][j] = __builtin_amdgcn_mfma_f32_16x16x32_bf16(ah[i], bh[j], acc[i][j], 0, 0, 0);
          acc[i][j] = __builtin_amdgcn_mfma_f32_16x16x32_bf16(ah[i], bl[j], acc[i][j], 0, 0, 0);
          acc[i][j] = __builtin_amdgcn_mfma_f32_16x16x32_bf16(al[i], bh[j], acc[i][j], 0, 0, 0);
        }
    }
    __syncthreads();
  }
  // C/D layout per 16x16: row(n) = quad*4 + r, col(m) = l15  [verified round 7, absmax 0]
  if (q16){
    short* Cb = (short*)Cm + (size_t)b * NN * NN;
    #pragma unroll
    for (int i = 0; i < 4; i++)
      #pragma unroll
      for (int j = 0; j < 4; j++)
        #pragma unroll
        for (int r = 0; r < 4; r++){
          int n = n0 + wn + i * 16 + quad * 4 + r;
          int m = m0 + wm + j * 16 + l15;
          float q = rintf(fminf(fmaxf(acc[i][j][r] * QS12, -32766.0f), 32766.0f));
          Cb[(size_t)n * NN + m] = (short)(int)q;
        }
  } else {
    float* Cb = (float*)Cm + (size_t)b * NN * NN;
    #pragma unroll
    for (int i = 0; i < 4; i++)
      #pragma unroll
      for (int j = 0; j < 4; j++)
        #pragma unroll
        for (int r = 0; r < 4; r++){
          int n = n0 + wn + i * 16 + quad * 4 + r;
          int m = m0 + wm + j * 16 + l15;
          Cb[(size_t)n * NN + m] = acc[i][j][r];
        }
  }
}

// ---- per-row logsumexp (nat domain, for k_fva)
__global__ void k_rowstats(const float* __restrict__ Mb, float* __restrict__ lse){
  int row = blockIdx.x * 4 + (threadIdx.x >> 6);
  int lane = threadIdx.x & 63;
  const float* p = Mb + (size_t)row * NN;
  float x[16]; float mx = -3.402823466e38f;
  #pragma unroll
  for (int k = 0; k < 16; k++){ x[k] = p[lane + 64 * k]; mx = fmaxf(mx, x[k]); }
  mx = wmax(mx);
  float s = 0.0f;
  #pragma unroll
  for (int k = 0; k < 16; k++) s += expf(x[k] - mx);
  s = wsum(s);
  if (lane == 0) lse[row] = mx + logf(s);
}

// ---- row stats (nat) + argmax + correct_match + global absmax
__global__ void k_rowstats_argmax(const float* __restrict__ Mb, float* __restrict__ lse,
                                  float* __restrict__ accs){
  __shared__ float axs[4];
  int row = blockIdx.x * 4 + (threadIdx.x >> 6);
  int wid = threadIdx.x >> 6;
  int lane = threadIdx.x & 63;
  const float* p = Mb + (size_t)row * NN;
  float x[16]; float mx = -3.402823466e38f; float ax = 0.0f;
  float bm = -3.402823466e38f; int bi = 0;
  #pragma unroll
  for (int k = 0; k < 16; k++){
    x[k] = p[lane + 64 * k];
    mx = fmaxf(mx, x[k]);
    ax = fmaxf(ax, fabsf(x[k]));
    if (x[k] > bm){ bm = x[k]; bi = lane + 64 * k; }
  }
  mx = wmax(mx); ax = wmax(ax);
  #pragma unroll
  for (int o = 32; o > 0; o >>= 1){
    float om = __shfl_xor(bm, o, 64); int oi = __shfl_xor(bi, o, 64);
    if (om > bm || (om == bm && oi < bi)){ bm = om; bi = oi; }
  }
  float s = 0.0f;
  #pragma unroll
  for (int k = 0; k < 16; k++) s += expf(x[k] - mx);
  s = wsum(s);
  if (lane == 0){
    lse[row] = mx + logf(s);
    axs[wid] = ax;
    if (bi == (row & 1023)) atomicAdd(&accs[48 + (blockIdx.x & 15)], 1.0f);
  }
  __syncthreads();
  if (threadIdx.x == 0){
    float a = fmaxf(fmaxf(axs[0], axs[1]), fmaxf(axs[2], axs[3]));
    atomicMax((int*)&accs[64 + (blockIdx.x & 15)], __float_as_int(a));
  }
}

__global__ void k_scale(float* accs){
  if (threadIdx.x == 0){
    float g = 0.0f;
    for (int j = 0; j < 16; j++) g = fmaxf(g, accs[64 + j]);
    accs[80] = (g * INV_TAU * LOG2E) / 32766.0f;   // IQ2
  }
}

// ---- fva_quarter[z][b,n,c] = sum_{m in quarter z} exp(M[b,n,m]-lse1[b,n]) * f1[(b+1)&7][m][c]
// Lean LDS (~20.6KB -> 7 blocks/CU); grid (32, 8, 4) = 1024 blocks.
__global__ __launch_bounds__(256) void k_fva(const float* __restrict__ Mb,
                                             const float* __restrict__ lse1,
                                             const float* __restrict__ f1,
                                             float* __restrict__ fva){
  __shared__ float Ps[32][36];    // [m][row(n)], 32 n-rows
  __shared__ float Bs[32][128];   // [m][c]
  int b = blockIdx.y;
  int z = blockIdx.z;
  int n0 = blockIdx.x * 32;
  int mbase = z * 256;
  const float* Mrow = Mb + (size_t)(b * NN + n0) * NN + mbase;
  const float* fa = f1 + (size_t)((b + 1) & 7) * NN * NC + (size_t)mbase * NC;
  const float* lseb = lse1 + b * NN + n0;
  float* fvaH = fva + (size_t)z * 1048576;
  int tid = threadIdx.x;
  int ty = tid >> 5, tx = tid & 31;
  float acc[4][4] = {};
  for (int mm = 0; mm < 256; mm += 32){
    {  // stage Ps: 32 rows x 32 m = 256 float4 slots, 1 per thread
      int r = tid >> 3, m4 = tid & 7;
      float l = lseb[r];
      float4 v = *(const float4*)(Mrow + (size_t)r * NN + mm + m4 * 4);
      Ps[m4*4+0][r] = expf(v.x - l); Ps[m4*4+1][r] = expf(v.y - l);
      Ps[m4*4+2][r] = expf(v.z - l); Ps[m4*4+3][r] = expf(v.w - l);
    }
    #pragma unroll
    for (int i = 0; i < 4; i++){  // stage Bs: 32 m x 128 c = 1024 float4
      int t = tid + 256 * i;
      int m = t >> 5, c4 = t & 31;
      *(float4*)&Bs[m][c4 * 4] = *(const float4*)(fa + (size_t)(mm + m) * NC + c4 * 4);
    }
    __syncthreads();
    #pragma unroll 8
    for (int m = 0; m < 32; m++){
      float4 a4 = *(const float4*)&Ps[m][ty * 4];
      float4 b4 = *(const float4*)&Bs[m][tx * 4];
      acc[0][0] += a4.x*b4.x; acc[0][1] += a4.x*b4.y; acc[0][2] += a4.x*b4.z; acc[0][3] += a4.x*b4.w;
      acc[1][0] += a4.y*b4.x; acc[1][1] += a4.y*b4.y; acc[1][2] += a4.y*b4.z; acc[1][3] += a4.y*b4.w;
      acc[2][0] += a4.z*b4.x; acc[2][1] += a4.z*b4.y; acc[2][2] += a4.z*b4.z; acc[2][3] += a4.z*b4.w;
      acc[3][0] += a4.w*b4.x; acc[3][1] += a4.w*b4.y; acc[3][2] += a4.w*b4.z; acc[3][3] += a4.w*b4.w;
    }
    __syncthreads();
  }
  #pragma unroll
  for (int i = 0; i < 4; i++){
    float4 o = make_float4(acc[i][0], acc[i][1], acc[i][2], acc[i][3]);
    *(float4*)(fvaH + ((size_t)(b * NN + n0 + ty * 4 + i)) * NC + tx * 4) = o;
  }
}

// ---- merge 4 fva partials + bf16 hi/lo split
__global__ __launch_bounds__(256) void k_split(const float* __restrict__ A,
                                               u16* __restrict__ H, u16* __restrict__ L){
  int g = blockIdx.x * 256 + threadIdx.x;   // 262144 threads x 4 elems
  float4 a = ((const float4*)A)[g];
  float4 b = ((const float4*)(A + 1048576))[g];
  float4 c = ((const float4*)(A + 2097152))[g];
  float4 d = ((const float4*)(A + 3145728))[g];
  float s[4] = { a.x + b.x + c.x + d.x, a.y + b.y + c.y + d.y,
                 a.z + b.z + c.z + d.z, a.w + b.w + c.w + d.w };
  u16 h[4], l[4];
  #pragma unroll
  for (int k = 0; k < 4; k++){
    h[k] = f2bf(s[k]);
    l[k] = f2bf(s[k] - bf2f(h[k]));
  }
  uint2 hw, lw;
  hw.x = (unsigned)h[0] | ((unsigned)h[1] << 16); hw.y = (unsigned)h[2] | ((unsigned)h[3] << 16);
  lw.x = (unsigned)l[0] | ((unsigned)l[1] << 16); lw.y = (unsigned)l[2] | ((unsigned)l[3] << 16);
  ((uint2*)H)[g] = hw; ((uint2*)L)[g] = lw;
}

// ---- quantize L2 = M*INV_TAU*LOG2E to int16 + transposed copy
__global__ __launch_bounds__(256) void k_quant_t(const float* __restrict__ Mb,
                                                 const float* __restrict__ accs,
                                                 short* __restrict__ Q,
                                                 short* __restrict__ Qt){
  __shared__ float T[64][68];
  float KQ = (INV_TAU * LOG2E) / accs[80];
  int b = blockIdx.z; int n0 = blockIdx.y * 64, m0 = blockIdx.x * 64;
  const float* src = Mb + (size_t)b * NN * NN;
  int tid = threadIdx.x;
  #pragma unroll
  for (int i = 0; i < 4; i++){
    int t = tid + 256 * i; int r = t >> 4, c4 = t & 15;
    float4 v = *(const float4*)(src + (size_t)(n0 + r) * NN + m0 + c4 * 4);
    float q0 = rintf(v.x * KQ);
    float q1 = rintf(v.y * KQ);
    float q2 = rintf(v.z * KQ);
    float q3 = rintf(v.w * KQ);
    T[r][c4*4+0] = q0; T[r][c4*4+1] = q1; T[r][c4*4+2] = q2; T[r][c4*4+3] = q3;
    int2 w;
    w.x = ((int)q0 & 0xFFFF) | ((int)q1 << 16);
    w.y = ((int)q2 & 0xFFFF) | ((int)q3 << 16);
    *(int2*)(Q + ((size_t)(b * NN + n0 + r) * NN + m0 + c4 * 4)) = w;
  }
  __syncthreads();
  #pragma unroll
  for (int i = 0; i < 4; i++){
    int t = tid + 256 * i; int r = t >> 4, c4 = t & 15;
    float q0 = T[c4*4+0][r], q1 = T[c4*4+1][r], q2 = T[c4*4+2][r], q3 = T[c4*4+3][r];
    int2 w;
    w.x = ((int)q0 & 0xFFFF) | ((int)q1 << 16);
    w.y = ((int)q2 & 0xFFFF) | ((int)q3 << 16);
    *(int2*)(Qt + ((size_t)(b * NN + m0 + r) * NN + n0 + c4 * 4)) = w;
  }
}

// ---- sinkhorn half-pass (log2 domain, 1 row/wave, 2048 blocks = 32 waves/CU)
__global__ __launch_bounds__(256) void k_pass(const short* __restrict__ Q,
                                              const float* __restrict__ invec,
                                              float* __restrict__ outvec,
                                              const float* __restrict__ accs){
  const float IQ2 = accs[80];
  int tid = threadIdx.x, wid = tid >> 6, lane = tid & 63;
  int row = blockIdx.x * 4 + wid;      // 2048 blocks
  int b = row >> 10;
  float hh[16];
  load16(invec + b * NN, lane, hh);
  const int4* qp = (const int4*)(Q + (size_t)row * NN);
  int4 wa = qp[lane], wb = qp[64 + lane];
  int qq[8] = { wa.x, wa.y, wa.z, wa.w, wb.x, wb.y, wb.z, wb.w };
  float x[16]; float mx = -3.402823466e38f;
  #pragma unroll
  for (int k = 0; k < 8; k++){
    x[2*k]   = fmaf((float)(short)(qq[k]), IQ2, hh[2*k]);
    x[2*k+1] = fmaf((float)(qq[k] >> 16),  IQ2, hh[2*k+1]);
    mx = fmaxf(mx, fmaxf(x[2*k], x[2*k+1]));
  }
  mx = wmax(mx);
  float s = 0.0f;
  #pragma unroll
  for (int k = 0; k < 16; k++) s += fexp2(x[k] - mx);
  s = wsum(s);
  if (lane == 0) outvec[row] = -(mx + flog2(s));
}

// ---- fused final reduction (log2 domain, pc in padded split LDS)
__global__ __launch_bounds__(1024) void k_final(const short* __restrict__ Q,
                                                const short* __restrict__ Q12,
                                                const float* __restrict__ lse2,
                                                const float* __restrict__ P2,
                                                const float* __restrict__ V2,
                                                const float* __restrict__ pc0,
                                                float* __restrict__ accs){
  __shared__ float pcx[1152], pcy[1152], pcz[1152];
  __shared__ float partial[3][16];
  const float IQ2 = accs[80];
  const float IQ12_2 = (400.0f / 32766.0f) * LOG2E;
  int tid = threadIdx.x, wid = tid >> 6, lane = tid & 63;
  int row = blockIdx.x * 16 + wid;     // grid 512
  int b = row >> 10, n = row & 1023;
  {
    int m = tid;
    const float* pg = pc0 + (size_t)b * 3072 + 3 * m;
    float px = pg[0], py = pg[1], pz = pg[2];
    int idx = m + (m >> 3);
    pcx[idx] = px; pcy[idx] = py; pcz[idx] = pz;
  }
  __syncthreads();
  const int4* qp  = (const int4*)(Q   + (size_t)row * NN);
  const int4* qp2 = (const int4*)(Q12 + (size_t)row * NN);
  int4 a1 = qp[lane],  b1 = qp[64 + lane];
  int4 a2 = qp2[lane], b2 = qp2[64 + lane];
  int q1[8] = { a1.x, a1.y, a1.z, a1.w, b1.x, b1.y, b1.z, b1.w };
  int q2[8] = { a2.x, a2.y, a2.z, a2.w, b2.x, b2.y, b2.z, b2.w };
  float L[16], c[16];
  float cmx = -3.402823466e38f;
  #pragma unroll
  for (int k = 0; k < 8; k++){
    L[2*k]   = (float)(short)(q1[k]) * IQ2;
    L[2*k+1] = (float)(q1[k] >> 16)  * IQ2;
    c[2*k]   = (float)(short)(q2[k]) * IQ12_2;
    c[2*k+1] = (float)(q2[k] >> 16)  * IQ12_2;
    cmx = fmaxf(cmx, fmaxf(c[2*k], c[2*k+1]));
  }
  cmx = wmax(cmx);
  float cs = 0.0f;
  #pragma unroll
  for (int k = 0; k < 16; k++) cs += fexp2(c[k] - cmx);
  cs = wsum(cs);
  float lse12r = cmx + flog2(cs);
  float vv[16];
  load16(V2 + b * NN, lane, vv);
  int nidx = n + (n >> 3);
  float qx = pcx[nidx], qy = pcy[nidx], qz = pcz[nidx];
  float c1row = -lse2[row] * LOG2E;
  float Prow = P2[row];
  float sl = 0.0f, slc = 0.0f, spi = 0.0f;
  #pragma unroll
  for (int k = 0; k < 16; k++){
    int m = (k < 8) ? (8 * lane + k) : (512 + 8 * lane + k - 8);
    int midx = m + (m >> 3);
    float e1 = fexp2(fmaf(L[k], 0.3f, c1row));
    float sk = fexp2(L[k] + Prow + vv[k]);
    float e2 = fexp2(c[k] - lse12r);
    float dx = qx - pcx[midx], dy = qy - pcy[midx], dz = qz - pcz[midx];
    float d = sqrtf(sqrtf(dx*dx + dy*dy + dz*dz));
    sl  += d * (e1 + e2);
    slc += fabsf(sk - e1);
    spi += fabsf(((m == n) ? 1.0f : 0.0f) - sk);
  }
  sl = wsum(sl); slc = wsum(slc); spi = wsum(spi);
  if (lane == 0){ partial[0][wid] = sl; partial[1][wid] = slc; partial[2][wid] = spi; }
  __syncthreads();
  if (tid < 3){
    float t = 0.0f;
    #pragma unroll
    for (int i = 0; i < 16; i++) t += partial[tid][i];
    atomicAdd(&accs[tid * 16 + (blockIdx.x & 15)], t);
  }
}

__global__ void k_finalize(const float* __restrict__ accs, float* __restrict__ out){
  if (threadIdx.x == 0){
    float sl = 0, slc = 0, spi = 0, scm = 0;
    for (int j = 0; j < 16; j++){
      sl += accs[j]; slc += accs[16 + j]; spi += accs[32 + j]; scm += accs[48 + j];
    }
    float loss = sl / 1024.0f;
    float Lc   = 3.0f * slc / 1024.0f;
    float perm = 3.0f * spi / 1024.0f;
    float total = loss + Lc;
    out[0] = total / 8.0f;
    out[1] = loss / 8.0f;
    out[2] = Lc / 8.0f;
    out[3] = scm / 8.0f;
    out[4] = perm / 8.0f;
  }
}

extern "C" void kernel_launch(void* const* d_in, const int* in_sizes, int n_in,
                              void* d_out, int out_size, void* d_ws, size_t ws_size,
                              hipStream_t stream){
  const float* feats = (const float*)d_in[0];   // [16,1024,128]
  const float* pc0   = (const float*)d_in[1];   // [8,1024,3]
  float* out = (float*)d_out;                   // 5 scalars

  float* ws   = (float*)d_ws;
  float* f1   = ws;                       // 1,048,576 f
  u16* f1h    = (u16*)(f1 + 1048576);     // 1,048,576 u16
  u16* f1l    = f1h + 1048576;
  u16* f2h    = f1l + 1048576;
  u16* f2l    = f2h + 1048576;
  u16* fvh    = f2l + 1048576;
  u16* fvl    = fvh + 1048576;
  float* fva  = (float*)(fvl + 1048576);  // 4,194,304 f (four m-quarters)
  float* M    = fva + 4194304;            // 8,388,608 f
  short* Q    = (short*)(M + 8388608);    // 8,388,608 s16 (log2-scaled)
  short* Qt   = Q + 8388608;              // 8,388,608 s16 (later reused as Q12)
  float* lse1 = (float*)(Qt + 8388608);   // 8192
  float* lse2 = lse1 + 8192;
  float* P    = lse2 + 8192;
  float* V    = P + 8192;
  float* accs = V + 8192;                 // 160
  if (ws_size < (size_t)((char*)(accs + 160) - (char*)ws)) return;

  k_init<<<32, 256, 0, stream>>>(accs, P, V);
  k_normalize<<<16384, 64, 0, stream>>>(feats, f1, f1h, f1l, f2h, f2l);
  // corr_1a = f1 @ roll(f1)^T  (MFMA v2, LDS-staged)
  k_gemm_mfma<<<dim3(8,8,8), 256, 0, stream>>>(f1h, f1l, f1h, f1l, M, 1, 0);
  k_rowstats<<<2048, 256, 0, stream>>>(M, lse1);
  // f1_via_fa = softmax(corr_1a) @ roll(f1) — m-split x4, lean LDS (7 blocks/CU)
  k_fva<<<dim3(32,8,4), 256, 0, stream>>>(M, lse1, f1, fva);
  k_split<<<1024, 256, 0, stream>>>(fva, fvh, fvl);
  // corr_1a2 = fva @ f2^T  (MFMA v2)
  k_gemm_mfma<<<dim3(8,8,8), 256, 0, stream>>>(fvh, fvl, f2h, f2l, M, 0, 0);
  k_rowstats_argmax<<<2048, 256, 0, stream>>>(M, lse2, accs);
  k_scale<<<1, 64, 0, stream>>>(accs);
  k_quant_t<<<dim3(16,16,8), 256, 0, stream>>>(M, accs, Q, Qt);
  // sinkhorn: 30 x (row pass -> P, col pass -> V), log2 domain
  for (int it = 0; it < 30; it++){
    k_pass<<<2048, 256, 0, stream>>>(Q,  V, P, accs);
    k_pass<<<2048, 256, 0, stream>>>(Qt, P, V, accs);
  }
  // corr_12 = f1 @ f2^T as int16 (MFMA v2), into the now-dead Qt buffer
  k_gemm_mfma<<<dim3(8,8,8), 256, 0, stream>>>(f1h, f1l, f2h, f2l, Qt, 0, 1);
  k_final<<<512, 1024, 0, stream>>>(Q, Qt, lse2, P, V, pc0, accs);
  k_finalize<<<1, 64, 0, stream>>>(accs, out);
}

// Round 11
// 461.444 us; speedup vs baseline: 1.4194x; 1.0288x over previous
//
#include <hip/hip_runtime.h>
#include <math.h>

#define NB 8
#define NN 1024
#define NC 128
#define INV_TAU (1.0f/0.3f)
#define LOG2E 1.44269504088896340736f

typedef unsigned short u16;
typedef short bf16x8 __attribute__((ext_vector_type(8)));
typedef float f32x4 __attribute__((ext_vector_type(4)));

__device__ __forceinline__ float wsum(float v){
  #pragma unroll
  for (int o = 32; o > 0; o >>= 1) v += __shfl_xor(v, o, 64);
  return v;
}
__device__ __forceinline__ float wmax(float v){
  #pragma unroll
  for (int o = 32; o > 0; o >>= 1) v = fmaxf(v, __shfl_xor(v, o, 64));
  return v;
}
__device__ __forceinline__ float fexp2(float x){ return __builtin_amdgcn_exp2f(x); }
__device__ __forceinline__ float flog2(float x){ return __builtin_amdgcn_logf(x); }
__device__ __forceinline__ u16 f2bf(float f){     // RNE bf16, any finite sign
  unsigned u = __float_as_uint(f);
  return (u16)((u + 0x7FFFu + ((u >> 16) & 1u)) >> 16);
}
__device__ __forceinline__ float bf2f(u16 h){ return __uint_as_float((unsigned)h << 16); }

__device__ __forceinline__ void load16(const float* __restrict__ base, int lane, float* o){
  float4 a = *(const float4*)(base + 8 * lane);
  float4 b = *(const float4*)(base + 8 * lane + 4);
  float4 c = *(const float4*)(base + 512 + 8 * lane);
  float4 d = *(const float4*)(base + 512 + 8 * lane + 4);
  o[0]=a.x; o[1]=a.y; o[2]=a.z; o[3]=a.w; o[4]=b.x; o[5]=b.y; o[6]=b.z; o[7]=b.w;
  o[8]=c.x; o[9]=c.y; o[10]=c.z; o[11]=c.w; o[12]=d.x; o[13]=d.y; o[14]=d.z; o[15]=d.w;
}

// accs: [0:16) loss | [16:32) lc | [32:48) perm | [48:64) cm | [64:80) gmax | 80 IQ2
__global__ void k_init(float* accs, float* P, float* V){
  int i = blockIdx.x * 256 + threadIdx.x;   // 8192 threads
  if (i < 160) accs[i] = 0.0f;
  P[i] = 0.0f; V[i] = 0.0f;
}

// ---- L2 normalize * 20; emit f1 fp32 + hi/lo bf16 splits of f1,f2
__global__ void k_normalize(const float* __restrict__ feats, float* __restrict__ f1,
                            u16* __restrict__ f1h, u16* __restrict__ f1l,
                            u16* __restrict__ f2h, u16* __restrict__ f2l){
  int vid = blockIdx.x;
  int lane = threadIdx.x;          // 64 threads, 2 floats each
  const float* src = feats + (size_t)vid * NC;
  float2 x = *(const float2*)(src + lane * 2);
  float s = wsum(x.x * x.x + x.y * x.y);
  float sc = 20.0f / fmaxf(sqrtf(s), 1e-12f);
  int batch = vid >> 10, n = vid & 1023;
  size_t off = ((size_t)(batch >> 1) * NN + n) * NC + 2 * lane;
  float2 y; y.x = x.x * sc; y.y = x.y * sc;
  u16 h0 = f2bf(y.x), h1 = f2bf(y.y);
  u16 l0 = f2bf(y.x - bf2f(h0)), l1 = f2bf(y.y - bf2f(h1));
  unsigned hw = (unsigned)h0 | ((unsigned)h1 << 16);
  unsigned lw = (unsigned)l0 | ((unsigned)l1 << 16);
  if (batch & 1){
    *(unsigned*)(f2h + off) = hw; *(unsigned*)(f2l + off) = lw;
  } else {
    *(float2*)(f1 + off) = y;
    *(unsigned*)(f1h + off) = hw; *(unsigned*)(f1l + off) = lw;
  }
}

// ---- transpose f1 splits: f1T[b][c][m] = f1[b][m][c] (hi and lo)
__global__ __launch_bounds__(256) void k_transp(const u16* __restrict__ H,
                                                const u16* __restrict__ L,
                                                u16* __restrict__ TH, u16* __restrict__ TL){
  __shared__ u16 T[64][72];
  int b = blockIdx.z, n0 = blockIdx.y * 64, c0 = blockIdx.x * 64;
  int tid = threadIdx.x;
  #pragma unroll
  for (int pass = 0; pass < 2; pass++){
    const u16* src = (pass ? L : H) + (size_t)b * NN * NC;
    u16* dst = (pass ? TL : TH) + (size_t)b * NC * NN;
    #pragma unroll
    for (int i = 0; i < 2; i++){
      int unit = tid + 256 * i;       // 512 units of 8
      int r = unit >> 3, u = unit & 7;
      *(uint4*)&T[r][u * 8] = *(const uint4*)(src + (size_t)(n0 + r) * NC + c0 + u * 8);
    }
    __syncthreads();
    #pragma unroll
    for (int i = 0; i < 2; i++){
      int unit = tid + 256 * i;
      int c = unit >> 3, nu = unit & 7;
      u16 vals[8];
      #pragma unroll
      for (int k = 0; k < 8; k++) vals[k] = T[nu * 8 + k][c];
      *(uint4*)(dst + (size_t)(c0 + c) * NN + n0 + nu * 8) = *(uint4*)vals;
    }
    __syncthreads();
  }
}

// ---- MFMA GEMM v2 (LDS-staged, 128x128 tile): C[b][n][m] = sum_k A[b][n][k]*B[(b+rollB)&7][m][k]
__global__ __launch_bounds__(256) void k_gemm_mfma(const u16* __restrict__ Ah_g,
                                                   const u16* __restrict__ Al_g,
                                                   const u16* __restrict__ Bh_g,
                                                   const u16* __restrict__ Bl_g,
                                                   void* __restrict__ Cm,
                                                   int rollB, int q16){
  __shared__ __align__(16) u16 As_h[128][64];   // 16 KB each, 64 KB total
  __shared__ __align__(16) u16 As_l[128][64];
  __shared__ __align__(16) u16 Bs_h[128][64];
  __shared__ __align__(16) u16 Bs_l[128][64];
  const float QS12 = 32766.0f / 400.0f;
  int b = blockIdx.z;
  int m0 = blockIdx.x * 128, n0 = blockIdx.y * 128;
  int tid = threadIdx.x, w = tid >> 6, lane = tid & 63;
  int quad = lane >> 4, l15 = lane & 15;
  int wn = (w >> 1) * 64, wm = (w & 1) * 64;
  size_t abase = (size_t)b * NN * NC;
  size_t bbase = (size_t)((b + rollB) & 7) * NN * NC;
  f32x4 z = {0.0f, 0.0f, 0.0f, 0.0f};
  f32x4 acc[4][4] = {{z,z,z,z},{z,z,z,z},{z,z,z,z},{z,z,z,z}};
  for (int kk = 0; kk < NC; kk += 64){
    #pragma unroll
    for (int i2 = 0; i2 < 4; i2++){
      int uidx = tid + 256 * i2;          // 0..1023
      int r = uidx >> 3, u = uidx & 7;
      int su = ((u ^ (r & 7)) << 3);
      size_t goA = abase + (size_t)(n0 + r) * NC + kk + u * 8;
      size_t goB = bbase + (size_t)(m0 + r) * NC + kk + u * 8;
      *(uint4*)&As_h[r][su] = *(const uint4*)(Ah_g + goA);
      *(uint4*)&As_l[r][su] = *(const uint4*)(Al_g + goA);
      *(uint4*)&Bs_h[r][su] = *(const uint4*)(Bh_g + goB);
      *(uint4*)&Bs_l[r][su] = *(const uint4*)(Bl_g + goB);
    }
    __syncthreads();
    #pragma unroll
    for (int c = 0; c < 2; c++){          // two K32 chunks per stage
      bf16x8 ah[4], al[4], bh[4], bl[4];
      #pragma unroll
      for (int i = 0; i < 4; i++){
        int rn = wn + i * 16 + l15;
        int sn = (((c * 4 + quad) ^ (rn & 7)) << 3);
        ah[i] = *(const bf16x8*)&As_h[rn][sn];
        al[i] = *(const bf16x8*)&As_l[rn][sn];
        int rm = wm + i * 16 + l15;
        int sm = (((c * 4 + quad) ^ (rm & 7)) << 3);
        bh[i] = *(const bf16x8*)&Bs_h[rm][sm];
        bl[i] = *(const bf16x8*)&Bs_l[rm][sm];
      }
      #pragma unroll
      for (int i = 0; i < 4; i++)
        #pragma unroll
        for (int j = 0; j < 4; j++){
          acc[i][j] = __builtin_amdgcn_mfma_f32_16x16x32_bf16(ah[i], bh[j], acc[i][j], 0, 0, 0);
          acc[i][j] = __builtin_amdgcn_mfma_f32_16x16x32_bf16(ah[i], bl[j], acc[i][j], 0, 0, 0);
          acc[i][j] = __builtin_amdgcn_mfma_f32_16x16x32_bf16(al[i], bh[j], acc[i][j], 0, 0, 0);
        }
    }
    __syncthreads();
  }
  if (q16){
    short* Cb = (short*)Cm + (size_t)b * NN * NN;
    #pragma unroll
    for (int i = 0; i < 4; i++)
      #pragma unroll
      for (int j = 0; j < 4; j++)
        #pragma unroll
        for (int r = 0; r < 4; r++){
          int n = n0 + wn + i * 16 + quad * 4 + r;
          int m = m0 + wm + j * 16 + l15;
          float q = rintf(fminf(fmaxf(acc[i][j][r] * QS12, -32766.0f), 32766.0f));
          Cb[(size_t)n * NN + m] = (short)(int)q;
        }
  } else {
    float* Cb = (float*)Cm + (size_t)b * NN * NN;
    #pragma unroll
    for (int i = 0; i < 4; i++)
      #pragma unroll
      for (int j = 0; j < 4; j++)
        #pragma unroll
        for (int r = 0; r < 4; r++){
          int n = n0 + wn + i * 16 + quad * 4 + r;
          int m = m0 + wm + j * 16 + l15;
          Cb[(size_t)n * NN + m] = acc[i][j][r];
        }
  }
}

// ---- per-row logsumexp (nat domain, for k_fva_mfma)
__global__ void k_rowstats(const float* __restrict__ Mb, float* __restrict__ lse){
  int row = blockIdx.x * 4 + (threadIdx.x >> 6);
  int lane = threadIdx.x & 63;
  const float* p = Mb + (size_t)row * NN;
  float x[16]; float mx = -3.402823466e38f;
  #pragma unroll
  for (int k = 0; k < 16; k++){ x[k] = p[lane + 64 * k]; mx = fmaxf(mx, x[k]); }
  mx = wmax(mx);
  float s = 0.0f;
  #pragma unroll
  for (int k = 0; k < 16; k++) s += expf(x[k] - mx);
  s = wsum(s);
  if (lane == 0) lse[row] = mx + logf(s);
}

// ---- row stats (nat) + argmax + correct_match + global absmax
__global__ void k_rowstats_argmax(const float* __restrict__ Mb, float* __restrict__ lse,
                                  float* __restrict__ accs){
  __shared__ float axs[4];
  int row = blockIdx.x * 4 + (threadIdx.x >> 6);
  int wid = threadIdx.x >> 6;
  int lane = threadIdx.x & 63;
  const float* p = Mb + (size_t)row * NN;
  float x[16]; float mx = -3.402823466e38f; float ax = 0.0f;
  float bm = -3.402823466e38f; int bi = 0;
  #pragma unroll
  for (int k = 0; k < 16; k++){
    x[k] = p[lane + 64 * k];
    mx = fmaxf(mx, x[k]);
    ax = fmaxf(ax, fabsf(x[k]));
    if (x[k] > bm){ bm = x[k]; bi = lane + 64 * k; }
  }
  mx = wmax(mx); ax = wmax(ax);
  #pragma unroll
  for (int o = 32; o > 0; o >>= 1){
    float om = __shfl_xor(bm, o, 64); int oi = __shfl_xor(bi, o, 64);
    if (om > bm || (om == bm && oi < bi)){ bm = om; bi = oi; }
  }
  float s = 0.0f;
  #pragma unroll
  for (int k = 0; k < 16; k++) s += expf(x[k] - mx);
  s = wsum(s);
  if (lane == 0){
    lse[row] = mx + logf(s);
    axs[wid] = ax;
    if (bi == (row & 1023)) atomicAdd(&accs[48 + (blockIdx.x & 15)], 1.0f);
  }
  __syncthreads();
  if (threadIdx.x == 0){
    float a = fmaxf(fmaxf(axs[0], axs[1]), fmaxf(axs[2], axs[3]));
    atomicMax((int*)&accs[64 + (blockIdx.x & 15)], __float_as_int(a));
  }
}

__global__ void k_scale(float* accs){
  if (threadIdx.x == 0){
    float g = 0.0f;
    for (int j = 0; j < 16; j++) g = fmaxf(g, accs[64 + j]);
    accs[80] = (g * INV_TAU * LOG2E) / 32766.0f;   // IQ2
  }
}

// ---- fva via MFMA: fva_q[z][b][n][c] = sum_{m in quarter z} P[n,m] * fa[m][c]
// P computed in staging: exp2((M - lse1)*LOG2E) -> hi/lo bf16. fa via pre-transposed f1T[c][m].
__global__ __launch_bounds__(256) void k_fva_mfma(const float* __restrict__ Mg,
                                                  const float* __restrict__ lse1,
                                                  const u16* __restrict__ f1Th,
                                                  const u16* __restrict__ f1Tl,
                                                  float* __restrict__ fva){
  __shared__ __align__(16) u16 Ph[128][64];
  __shared__ __align__(16) u16 Pl[128][64];
  __shared__ __align__(16) u16 Fh[128][64];
  __shared__ __align__(16) u16 Fl[128][64];
  int b = blockIdx.z, zq = blockIdx.x, ny = blockIdx.y;  // zq 0..3, ny 0..7
  int n0 = ny * 128, mbase = zq * 256;
  const float* Mb = Mg + ((size_t)(b * NN + n0)) * NN + mbase;
  const u16* fTh = f1Th + (size_t)((b + 1) & 7) * NC * NN;
  const u16* fTl = f1Tl + (size_t)((b + 1) & 7) * NC * NN;
  const float* lseb = lse1 + b * NN + n0;
  float* out = fva + (size_t)zq * 1048576 + ((size_t)(b * NN + n0)) * NC;
  int tid = threadIdx.x, w = tid >> 6, lane = tid & 63;
  int quad = lane >> 4, l15 = lane & 15;
  int wn = (w >> 1) * 64, wc = (w & 1) * 64;
  f32x4 z = {0.0f, 0.0f, 0.0f, 0.0f};
  f32x4 acc[4][4] = {{z,z,z,z},{z,z,z,z},{z,z,z,z},{z,z,z,z}};
  for (int mm = 0; mm < 256; mm += 64){
    #pragma unroll
    for (int i2 = 0; i2 < 4; i2++){
      int unit = tid + 256 * i2;        // 1024 units of 8 m
      int r = unit >> 3, u = unit & 7;
      int su = ((u ^ (r & 7)) << 3);
      // P row r (n-row): exp2 of M
      float l = lseb[r];
      const float* mp = Mb + (size_t)r * NN + mm + u * 8;
      float4 v0 = *(const float4*)mp, v1 = *(const float4*)(mp + 4);
      float p[8] = { fexp2((v0.x - l) * LOG2E), fexp2((v0.y - l) * LOG2E),
                     fexp2((v0.z - l) * LOG2E), fexp2((v0.w - l) * LOG2E),
                     fexp2((v1.x - l) * LOG2E), fexp2((v1.y - l) * LOG2E),
                     fexp2((v1.z - l) * LOG2E), fexp2((v1.w - l) * LOG2E) };
      u16 h[8], lo[8];
      #pragma unroll
      for (int k = 0; k < 8; k++){ h[k] = f2bf(p[k]); lo[k] = f2bf(p[k] - bf2f(h[k])); }
      uint4 hw, lw;
      hw.x = (unsigned)h[0] | ((unsigned)h[1] << 16);  hw.y = (unsigned)h[2] | ((unsigned)h[3] << 16);
      hw.z = (unsigned)h[4] | ((unsigned)h[5] << 16);  hw.w = (unsigned)h[6] | ((unsigned)h[7] << 16);
      lw.x = (unsigned)lo[0] | ((unsigned)lo[1] << 16); lw.y = (unsigned)lo[2] | ((unsigned)lo[3] << 16);
      lw.z = (unsigned)lo[4] | ((unsigned)lo[5] << 16); lw.w = (unsigned)lo[6] | ((unsigned)lo[7] << 16);
      *(uint4*)&Ph[r][su] = hw;
      *(uint4*)&Pl[r][su] = lw;
      // F row r (c-row): straight copy from f1T
      size_t fo = (size_t)r * NN + mbase + mm + u * 8;
      *(uint4*)&Fh[r][su] = *(const uint4*)(fTh + fo);
      *(uint4*)&Fl[r][su] = *(const uint4*)(fTl + fo);
    }
    __syncthreads();
    #pragma unroll
    for (int c2 = 0; c2 < 2; c2++){
      bf16x8 ph[4], pl[4], fh[4], fl[4];
      #pragma unroll
      for (int i = 0; i < 4; i++){
        int rn = wn + i * 16 + l15;
        int sn = (((c2 * 4 + quad) ^ (rn & 7)) << 3);
        ph[i] = *(const bf16x8*)&Ph[rn][sn];
        pl[i] = *(const bf16x8*)&Pl[rn][sn];
        int rc = wc + i * 16 + l15;
        int sc = (((c2 * 4 + quad) ^ (rc & 7)) << 3);
        fh[i] = *(const bf16x8*)&Fh[rc][sc];
        fl[i] = *(const bf16x8*)&Fl[rc][sc];
      }
      #pragma unroll
      for (int i = 0; i < 4; i++)
        #pragma unroll
        for (int j = 0; j < 4; j++){
          acc[i][j] = __builtin_amdgcn_mfma_f32_16x16x32_bf16(ph[i], fh[j], acc[i][j], 0, 0, 0);
          acc[i][j] = __builtin_amdgcn_mfma_f32_16x16x32_bf16(ph[i], fl[j], acc[i][j], 0, 0, 0);
          acc[i][j] = __builtin_amdgcn_mfma_f32_16x16x32_bf16(pl[i], fh[j], acc[i][j], 0, 0, 0);
        }
    }
    __syncthreads();
  }
  // out[n][c]: n = wn + i*16 + quad*4 + r, c = wc + j*16 + l15
  #pragma unroll
  for (int i = 0; i < 4; i++)
    #pragma unroll
    for (int j = 0; j < 4; j++)
      #pragma unroll
      for (int r = 0; r < 4; r++){
        int n = wn + i * 16 + quad * 4 + r;
        int c = wc + j * 16 + l15;
        out[(size_t)n * NC + c] = acc[i][j][r];
      }
}

// ---- merge 4 fva partials + bf16 hi/lo split
__global__ __launch_bounds__(256) void k_split(const float* __restrict__ A,
                                               u16* __restrict__ H, u16* __restrict__ L){
  int g = blockIdx.x * 256 + threadIdx.x;   // 262144 threads x 4 elems
  float4 a = ((const float4*)A)[g];
  float4 b = ((const float4*)(A + 1048576))[g];
  float4 c = ((const float4*)(A + 2097152))[g];
  float4 d = ((const float4*)(A + 3145728))[g];
  float s[4] = { a.x + b.x + c.x + d.x, a.y + b.y + c.y + d.y,
                 a.z + b.z + c.z + d.z, a.w + b.w + c.w + d.w };
  u16 h[4], l[4];
  #pragma unroll
  for (int k = 0; k < 4; k++){
    h[k] = f2bf(s[k]);
    l[k] = f2bf(s[k] - bf2f(h[k]));
  }
  uint2 hw, lw;
  hw.x = (unsigned)h[0] | ((unsigned)h[1] << 16); hw.y = (unsigned)h[2] | ((unsigned)h[3] << 16);
  lw.x = (unsigned)l[0] | ((unsigned)l[1] << 16); lw.y = (unsigned)l[2] | ((unsigned)l[3] << 16);
  ((uint2*)H)[g] = hw; ((uint2*)L)[g] = lw;
}

// ---- quantize L2 = M*INV_TAU*LOG2E to int16 + transposed copy
__global__ __launch_bounds__(256) void k_quant_t(const float* __restrict__ Mb,
                                                 const float* __restrict__ accs,
                                                 short* __restrict__ Q,
                                                 short* __restrict__ Qt){
  __shared__ float T[64][68];
  float KQ = (INV_TAU * LOG2E) / accs[80];
  int b = blockIdx.z; int n0 = blockIdx.y * 64, m0 = blockIdx.x * 64;
  const float* src = Mb + (size_t)b * NN * NN;
  int tid = threadIdx.x;
  #pragma unroll
  for (int i = 0; i < 4; i++){
    int t = tid + 256 * i; int r = t >> 4, c4 = t & 15;
    float4 v = *(const float4*)(src + (size_t)(n0 + r) * NN + m0 + c4 * 4);
    float q0 = rintf(v.x * KQ);
    float q1 = rintf(v.y * KQ);
    float q2 = rintf(v.z * KQ);
    float q3 = rintf(v.w * KQ);
    T[r][c4*4+0] = q0; T[r][c4*4+1] = q1; T[r][c4*4+2] = q2; T[r][c4*4+3] = q3;
    int2 w;
    w.x = ((int)q0 & 0xFFFF) | ((int)q1 << 16);
    w.y = ((int)q2 & 0xFFFF) | ((int)q3 << 16);
    *(int2*)(Q + ((size_t)(b * NN + n0 + r) * NN + m0 + c4 * 4)) = w;
  }
  __syncthreads();
  #pragma unroll
  for (int i = 0; i < 4; i++){
    int t = tid + 256 * i; int r = t >> 4, c4 = t & 15;
    float q0 = T[c4*4+0][r], q1 = T[c4*4+1][r], q2 = T[c4*4+2][r], q3 = T[c4*4+3][r];
    int2 w;
    w.x = ((int)q0 & 0xFFFF) | ((int)q1 << 16);
    w.y = ((int)q2 & 0xFFFF) | ((int)q3 << 16);
    *(int2*)(Qt + ((size_t)(b * NN + m0 + r) * NN + n0 + c4 * 4)) = w;
  }
}

// ---- sinkhorn half-pass (log2 domain, 1 row/wave, 512 blocks x 1024 thr = 32 waves/CU)
__global__ __launch_bounds__(1024) void k_pass(const short* __restrict__ Q,
                                               const float* __restrict__ invec,
                                               float* __restrict__ outvec,
                                               const float* __restrict__ accs){
  const float IQ2 = accs[80];
  int tid = threadIdx.x, wid = tid >> 6, lane = tid & 63;
  int row = blockIdx.x * 16 + wid;      // 512 blocks x 16 rows
  int b = row >> 10;
  float hh[16];
  load16(invec + b * NN, lane, hh);
  const int4* qp = (const int4*)(Q + (size_t)row * NN);
  int4 wa = qp[lane], wb = qp[64 + lane];
  int qq[8] = { wa.x, wa.y, wa.z, wa.w, wb.x, wb.y, wb.z, wb.w };
  float x[16]; float mx = -3.402823466e38f;
  #pragma unroll
  for (int k = 0; k < 8; k++){
    x[2*k]   = fmaf((float)(short)(qq[k]), IQ2, hh[2*k]);
    x[2*k+1] = fmaf((float)(qq[k] >> 16),  IQ2, hh[2*k+1]);
    mx = fmaxf(mx, fmaxf(x[2*k], x[2*k+1]));
  }
  mx = wmax(mx);
  float s = 0.0f;
  #pragma unroll
  for (int k = 0; k < 16; k++) s += fexp2(x[k] - mx);
  s = wsum(s);
  if (lane == 0) outvec[row] = -(mx + flog2(s));
}

// ---- fused final reduction (log2 domain, pc in padded split LDS)
__global__ __launch_bounds__(1024) void k_final(const short* __restrict__ Q,
                                                const short* __restrict__ Q12,
                                                const float* __restrict__ lse2,
                                                const float* __restrict__ P2,
                                                const float* __restrict__ V2,
                                                const float* __restrict__ pc0,
                                                float* __restrict__ accs){
  __shared__ float pcx[1152], pcy[1152], pcz[1152];
  __shared__ float partial[3][16];
  const float IQ2 = accs[80];
  const float IQ12_2 = (400.0f / 32766.0f) * LOG2E;
  int tid = threadIdx.x, wid = tid >> 6, lane = tid & 63;
  int row = blockIdx.x * 16 + wid;     // grid 512
  int b = row >> 10, n = row & 1023;
  {
    int m = tid;
    const float* pg = pc0 + (size_t)b * 3072 + 3 * m;
    float px = pg[0], py = pg[1], pz = pg[2];
    int idx = m + (m >> 3);
    pcx[idx] = px; pcy[idx] = py; pcz[idx] = pz;
  }
  __syncthreads();
  const int4* qp  = (const int4*)(Q   + (size_t)row * NN);
  const int4* qp2 = (const int4*)(Q12 + (size_t)row * NN);
  int4 a1 = qp[lane],  b1 = qp[64 + lane];
  int4 a2 = qp2[lane], b2 = qp2[64 + lane];
  int q1[8] = { a1.x, a1.y, a1.z, a1.w, b1.x, b1.y, b1.z, b1.w };
  int q2[8] = { a2.x, a2.y, a2.z, a2.w, b2.x, b2.y, b2.z, b2.w };
  float L[16], c[16];
  float cmx = -3.402823466e38f;
  #pragma unroll
  for (int k = 0; k < 8; k++){
    L[2*k]   = (float)(short)(q1[k]) * IQ2;
    L[2*k+1] = (float)(q1[k] >> 16)  * IQ2;
    c[2*k]   = (float)(short)(q2[k]) * IQ12_2;
    c[2*k+1] = (float)(q2[k] >> 16)  * IQ12_2;
    cmx = fmaxf(cmx, fmaxf(c[2*k], c[2*k+1]));
  }
  cmx = wmax(cmx);
  float cs = 0.0f;
  #pragma unroll
  for (int k = 0; k < 16; k++) cs += fexp2(c[k] - cmx);
  cs = wsum(cs);
  float lse12r = cmx + flog2(cs);
  float vv[16];
  load16(V2 + b * NN, lane, vv);
  int nidx = n + (n >> 3);
  float qx = pcx[nidx], qy = pcy[nidx], qz = pcz[nidx];
  float c1row = -lse2[row] * LOG2E;
  float Prow = P2[row];
  float sl = 0.0f, slc = 0.0f, spi = 0.0f;
  #pragma unroll
  for (int k = 0; k < 16; k++){
    int m = (k < 8) ? (8 * lane + k) : (512 + 8 * lane + k - 8);
    int midx = m + (m >> 3);
    float e1 = fexp2(fmaf(L[k], 0.3f, c1row));
    float sk = fexp2(L[k] + Prow + vv[k]);
    float e2 = fexp2(c[k] - lse12r);
    float dx = qx - pcx[midx], dy = qy - pcy[midx], dz = qz - pcz[midx];
    float d = sqrtf(sqrtf(dx*dx + dy*dy + dz*dz));
    sl  += d * (e1 + e2);
    slc += fabsf(sk - e1);
    spi += fabsf(((m == n) ? 1.0f : 0.0f) - sk);
  }
  sl = wsum(sl); slc = wsum(slc); spi = wsum(spi);
  if (lane == 0){ partial[0][wid] = sl; partial[1][wid] = slc; partial[2][wid] = spi; }
  __syncthreads();
  if (tid < 3){
    float t = 0.0f;
    #pragma unroll
    for (int i = 0; i < 16; i++) t += partial[tid][i];
    atomicAdd(&accs[tid * 16 + (blockIdx.x & 15)], t);
  }
}

__global__ void k_finalize(const float* __restrict__ accs, float* __restrict__ out){
  if (threadIdx.x == 0){
    float sl = 0, slc = 0, spi = 0, scm = 0;
    for (int j = 0; j < 16; j++){
      sl += accs[j]; slc += accs[16 + j]; spi += accs[32 + j]; scm += accs[48 + j];
    }
    float loss = sl / 1024.0f;
    float Lc   = 3.0f * slc / 1024.0f;
    float perm = 3.0f * spi / 1024.0f;
    float total = loss + Lc;
    out[0] = total / 8.0f;
    out[1] = loss / 8.0f;
    out[2] = Lc / 8.0f;
    out[3] = scm / 8.0f;
    out[4] = perm / 8.0f;
  }
}

extern "C" void kernel_launch(void* const* d_in, const int* in_sizes, int n_in,
                              void* d_out, int out_size, void* d_ws, size_t ws_size,
                              hipStream_t stream){
  const float* feats = (const float*)d_in[0];   // [16,1024,128]
  const float* pc0   = (const float*)d_in[1];   // [8,1024,3]
  float* out = (float*)d_out;                   // 5 scalars

  float* ws   = (float*)d_ws;
  float* f1   = ws;                       // 1,048,576 f
  u16* f1h    = (u16*)(f1 + 1048576);     // 1,048,576 u16 each
  u16* f1l    = f1h + 1048576;
  u16* f2h    = f1l + 1048576;
  u16* f2l    = f2h + 1048576;
  u16* f1Th   = f2l + 1048576;
  u16* f1Tl   = f1Th + 1048576;
  u16* fvh    = f1Tl + 1048576;
  u16* fvl    = fvh + 1048576;
  float* fva  = (float*)(fvl + 1048576);  // 4,194,304 f (four m-quarters)
  float* M    = fva + 4194304;            // 8,388,608 f
  short* Q    = (short*)(M + 8388608);    // 8,388,608 s16 (log2-scaled)
  short* Qt   = Q + 8388608;              // 8,388,608 s16 (later reused as Q12)
  float* lse1 = (float*)(Qt + 8388608);   // 8192
  float* lse2 = lse1 + 8192;
  float* P    = lse2 + 8192;
  float* V    = P + 8192;
  float* accs = V + 8192;                 // 160
  if (ws_size < (size_t)((char*)(accs + 160) - (char*)ws)) return;

  k_init<<<32, 256, 0, stream>>>(accs, P, V);
  k_normalize<<<16384, 64, 0, stream>>>(feats, f1, f1h, f1l, f2h, f2l);
  // f1T[c][m] for the fva MFMA B-operand
  k_transp<<<dim3(2,16,8), 256, 0, stream>>>(f1h, f1l, f1Th, f1Tl);
  // corr_1a = f1 @ roll(f1)^T  (MFMA v2, LDS-staged)
  k_gemm_mfma<<<dim3(8,8,8), 256, 0, stream>>>(f1h, f1l, f1h, f1l, M, 1, 0);
  k_rowstats<<<2048, 256, 0, stream>>>(M, lse1);
  // f1_via_fa = softmax(corr_1a) @ roll(f1) — MFMA, m-split x4
  k_fva_mfma<<<dim3(4,8,8), 256, 0, stream>>>(M, lse1, f1Th, f1Tl, fva);
  k_split<<<1024, 256, 0, stream>>>(fva, fvh, fvl);
  // corr_1a2 = fva @ f2^T  (MFMA v2)
  k_gemm_mfma<<<dim3(8,8,8), 256, 0, stream>>>(fvh, fvl, f2h, f2l, M, 0, 0);
  k_rowstats_argmax<<<2048, 256, 0, stream>>>(M, lse2, accs);
  k_scale<<<1, 64, 0, stream>>>(accs);
  k_quant_t<<<dim3(16,16,8), 256, 0, stream>>>(M, accs, Q, Qt);
  // sinkhorn: 30 x (row pass -> P, col pass -> V), log2 domain
  for (int it = 0; it < 30; it++){
    k_pass<<<512, 1024, 0, stream>>>(Q,  V, P, accs);
    k_pass<<<512, 1024, 0, stream>>>(Qt, P, V, accs);
  }
  // corr_12 = f1 @ f2^T as int16 (MFMA v2), into the now-dead Qt buffer
  k_gemm_mfma<<<dim3(8,8,8), 256, 0, stream>>>(f1h, f1l, f2h, f2l, Qt, 0, 1);
  k_final<<<512, 1024, 0, stream>>>(Q, Qt, lse2, P, V, pc0, accs);
  k_finalize<<<1, 64, 0, stream>>>(accs, out);
}